// Round 13
// baseline (10765.925 us; speedup 1.0000x reference)
//
#include <hip/hip_runtime.h>

#define GRIDN 256
#define SPAD 129
#define APAD 33
#define EPSF 1e-6f
#define SCAN_LDS_BYTES ((2 * 32 * SPAD + 2 * 64 * SPAD + 64 * APAD) * 4)

typedef __attribute__((ext_vector_type(8))) short bf16x8;
typedef __attribute__((ext_vector_type(4))) float f32x4;
typedef __attribute__((ext_vector_type(2))) float f32x2;

__device__ __forceinline__ ushort f2bf(float f) {
  unsigned u = __float_as_uint(f);
  u += 0x7FFFu + ((u >> 16) & 1u);
  return (ushort)(u >> 16);
}
__device__ __forceinline__ float bf2f(ushort u) {
  return __uint_as_float(((unsigned)u) << 16);
}
__device__ __forceinline__ float sigf(float x) { return 1.f / (1.f + expf(-x)); }

// ---- XCD-local (L2) coherent slot loads: sc0 bypasses L1, hits own-XCD L2 ----
__device__ __forceinline__ void scload8(const float* b, f32x2 (&o)[8]) {
  asm volatile(
      "global_load_dwordx2 %0, %8, off sc0\n\t"
      "global_load_dwordx2 %1, %9, off sc0\n\t"
      "global_load_dwordx2 %2, %10, off sc0\n\t"
      "global_load_dwordx2 %3, %11, off sc0\n\t"
      "global_load_dwordx2 %4, %12, off sc0\n\t"
      "global_load_dwordx2 %5, %13, off sc0\n\t"
      "global_load_dwordx2 %6, %14, off sc0\n\t"
      "global_load_dwordx2 %7, %15, off sc0\n\t"
      "s_waitcnt vmcnt(0)"
      : "=&v"(o[0]), "=&v"(o[1]), "=&v"(o[2]), "=&v"(o[3]),
        "=&v"(o[4]), "=&v"(o[5]), "=&v"(o[6]), "=&v"(o[7])
      : "v"(b), "v"(b + 8192), "v"(b + 16384), "v"(b + 24576),
        "v"(b + 32768), "v"(b + 40960), "v"(b + 49152), "v"(b + 57344)
      : "memory");
}
__device__ __forceinline__ void scload4(const float* b, f32x4 (&o)[4]) {
  asm volatile(
      "global_load_dwordx4 %0, %4, off sc0\n\t"
      "global_load_dwordx4 %1, %5, off sc0\n\t"
      "global_load_dwordx4 %2, %6, off sc0\n\t"
      "global_load_dwordx4 %3, %7, off sc0\n\t"
      "s_waitcnt vmcnt(0)"
      : "=&v"(o[0]), "=&v"(o[1]), "=&v"(o[2]), "=&v"(o[3])
      : "v"(b), "v"(b + 4), "v"(b + 8), "v"(b + 12)
      : "memory");
}

// ---------------- weight transpose + hi/lo split (5 weights fused, z-dim) ----------------
__global__ void cvt_wT_split5_kernel(const float* __restrict__ W0, const float* __restrict__ W1_,
                                     const float* __restrict__ W2_, const float* __restrict__ W3_,
                                     const float* __restrict__ W4_, ushort* __restrict__ H0,
                                     ushort* __restrict__ L0, ushort* __restrict__ H1,
                                     ushort* __restrict__ L1, ushort* __restrict__ H2,
                                     ushort* __restrict__ L2, ushort* __restrict__ H3,
                                     ushort* __restrict__ L3, ushort* __restrict__ H4,
                                     ushort* __restrict__ L4) {
  __shared__ float tile[64][65];
  int zz = blockIdx.z;
  const float* W = (zz == 0) ? W0 : (zz == 1) ? W1_ : (zz == 2) ? W2_ : (zz == 3) ? W3_ : W4_;
  ushort* WTh = (zz == 0) ? H0 : (zz == 1) ? H1 : (zz == 2) ? H2 : (zz == 3) ? H3 : H4;
  ushort* WTl = (zz == 0) ? L0 : (zz == 1) ? L1 : (zz == 2) ? L2 : (zz == 3) ? L3 : L4;
  int bk = blockIdx.x * 64, bn = blockIdx.y * 64;
  int tid = threadIdx.x;
  int r = tid >> 2, c0 = (tid & 3) * 16;
#pragma unroll
  for (int q = 0; q < 16; q += 4) {
    float4 v = *(const float4*)&W[(size_t)(bk + r) * 1024 + bn + c0 + q];
    tile[r][c0 + q] = v.x; tile[r][c0 + q + 1] = v.y;
    tile[r][c0 + q + 2] = v.z; tile[r][c0 + q + 3] = v.w;
  }
  __syncthreads();
  uint ph[8], pl[8];
#pragma unroll
  for (int q = 0; q < 8; ++q) {
    float v0 = tile[c0 + 2 * q][r], v1 = tile[c0 + 2 * q + 1][r];
    ushort h0 = f2bf(v0), h1 = f2bf(v1);
    ushort l0 = f2bf(v0 - bf2f(h0)), l1 = f2bf(v1 - bf2f(h1));
    ph[q] = (uint)h0 | ((uint)h1 << 16);
    pl[q] = (uint)l0 | ((uint)l1 << 16);
  }
  *(uint4*)&WTh[(size_t)(bn + r) * 1024 + bk + c0] = make_uint4(ph[0], ph[1], ph[2], ph[3]);
  *(uint4*)&WTh[(size_t)(bn + r) * 1024 + bk + c0 + 8] = make_uint4(ph[4], ph[5], ph[6], ph[7]);
  *(uint4*)&WTl[(size_t)(bn + r) * 1024 + bk + c0] = make_uint4(pl[0], pl[1], pl[2], pl[3]);
  *(uint4*)&WTl[(size_t)(bn + r) * 1024 + bk + c0 + 8] = make_uint4(pl[4], pl[5], pl[6], pl[7]);
}

// ---------------- fp32 -> bf16 hi/lo split (A-side) ----------------
__global__ void split_x_kernel(const float* __restrict__ src, ushort* __restrict__ dh,
                               ushort* __restrict__ dl, int n4) {
  int i = blockIdx.x * blockDim.x + threadIdx.x;
  int stride = gridDim.x * blockDim.x;
  for (; i < n4; i += stride) {
    float4 v = ((const float4*)src)[i];
    float a[4] = {v.x, v.y, v.z, v.w};
    ushort hh[4], ll[4];
#pragma unroll
    for (int q = 0; q < 4; ++q) {
      hh[q] = f2bf(a[q]);
      ll[q] = f2bf(a[q] - bf2f(hh[q]));
    }
    ((ushort4*)dh)[i] = make_ushort4(hh[0], hh[1], hh[2], hh[3]);
    ((ushort4*)dl)[i] = make_ushort4(ll[0], ll[1], ll[2], ll[3]);
  }
}

// ---------------- rope table ----------------
__global__ void rope_table_kernel(float* __restrict__ cosT, float* __restrict__ sinT) {
  int t = blockIdx.x, i = threadIdx.x; // i in [0,64)
  float inv = expf(-(float)i * (9.210340371976184f / 64.f)); // 10000^(-i/64)
  float f = (float)t * inv;
  cosT[t * 64 + i] = cosf(f);
  sinT[t * 64 + i] = sinf(f);
}

// ---------------- theta/eta/alpha small projections (fp32) ----------------
__global__ void proj_small_kernel(const float* __restrict__ x, const float* __restrict__ Wa,
                                  const float* __restrict__ We, const float* __restrict__ Wt,
                                  float* __restrict__ alp, float* __restrict__ eta,
                                  float* __restrict__ theta) {
  __shared__ float wl[24][SPAD];
  int row = blockIdx.x * 256 + threadIdx.x;
  float acc[24];
#pragma unroll
  for (int c = 0; c < 24; ++c) acc[c] = 0.f;
  for (int kc = 0; kc < 1024; kc += 128) {
    __syncthreads();
    for (int e = threadIdx.x; e < 24 * 128; e += 256) {
      int c = e >> 7, k = e & 127;
      const float* src = (c < 8) ? Wa : (c < 16) ? We : Wt;
      wl[c][k] = src[(size_t)(kc + k) * 8 + (c & 7)];
    }
    __syncthreads();
    for (int k = 0; k < 128; k += 4) {
      float4 xv = *(const float4*)&x[(size_t)row * 1024 + kc + k];
#pragma unroll
      for (int c = 0; c < 24; ++c) {
        float4 wv = *(const float4*)&wl[c][k];
        acc[c] += xv.x * wv.x + xv.y * wv.y + xv.z * wv.z + xv.w * wv.w;
      }
    }
  }
#pragma unroll
  for (int c = 0; c < 8; ++c) alp[(size_t)row * 8 + c] = sigf(acc[c]);
#pragma unroll
  for (int c = 0; c < 8; ++c) eta[(size_t)row * 8 + c] = sigf(acc[8 + c]);
#pragma unroll
  for (int c = 0; c < 8; ++c) theta[(size_t)row * 8 + c] = sigf(acc[16 + c]);
}

// ---------------- split-bf16 MFMA GEMM, A fp32 in-kernel split (gate only) ----------------
template <int EPI>
__global__ __launch_bounds__(256) void gemm_split_kernel(const float* __restrict__ A,
                                                         const ushort* __restrict__ BTh,
                                                         const ushort* __restrict__ BTl,
                                                         float* __restrict__ C, int M, int N) {
  __shared__ ushort sAh[128][40];
  __shared__ ushort sAl[128][40];
  __shared__ ushort sBh[128][40];
  __shared__ ushort sBl[128][40];
  const int K = 1024;
  int m0 = blockIdx.x * 128, n0 = blockIdx.y * 128;
  int tid = threadIdx.x;
  int w = tid >> 6, lane = tid & 63;
  int wr = (w >> 1) * 64, wc = (w & 1) * 64;
  f32x4 acc[4][4];
#pragma unroll
  for (int i = 0; i < 4; ++i)
#pragma unroll
    for (int jq = 0; jq < 4; ++jq) acc[i][jq] = (f32x4){0.f, 0.f, 0.f, 0.f};
  int lr = tid >> 1, ls = (tid & 1) * 16;
  const float* ga = A + (size_t)(m0 + lr) * K + ls;
  const ushort* gbh = BTh + (size_t)(n0 + lr) * K + ls;
  const ushort* gbl = BTl + (size_t)(n0 + lr) * K + ls;
  for (int k0 = 0; k0 < K; k0 += 32) {
    float av[16];
    *(float4*)&av[0] = *(const float4*)(ga + k0);
    *(float4*)&av[4] = *(const float4*)(ga + k0 + 4);
    *(float4*)&av[8] = *(const float4*)(ga + k0 + 8);
    *(float4*)&av[12] = *(const float4*)(ga + k0 + 12);
    uint4 bh0 = *(const uint4*)(gbh + k0);
    uint4 bh1 = *(const uint4*)(gbh + k0 + 8);
    uint4 bl0 = *(const uint4*)(gbl + k0);
    uint4 bl1 = *(const uint4*)(gbl + k0 + 8);
    uint ph[8], pl[8];
#pragma unroll
    for (int q = 0; q < 8; ++q) {
      float v0 = av[2 * q], v1 = av[2 * q + 1];
      ushort h0 = f2bf(v0), h1 = f2bf(v1);
      ushort l0 = f2bf(v0 - bf2f(h0)), l1 = f2bf(v1 - bf2f(h1));
      ph[q] = (uint)h0 | ((uint)h1 << 16);
      pl[q] = (uint)l0 | ((uint)l1 << 16);
    }
    __syncthreads();
    *(uint4*)&sAh[lr][ls] = make_uint4(ph[0], ph[1], ph[2], ph[3]);
    *(uint4*)&sAh[lr][ls + 8] = make_uint4(ph[4], ph[5], ph[6], ph[7]);
    *(uint4*)&sAl[lr][ls] = make_uint4(pl[0], pl[1], pl[2], pl[3]);
    *(uint4*)&sAl[lr][ls + 8] = make_uint4(pl[4], pl[5], pl[6], pl[7]);
    *(uint4*)&sBh[lr][ls] = bh0; *(uint4*)&sBh[lr][ls + 8] = bh1;
    *(uint4*)&sBl[lr][ls] = bl0; *(uint4*)&sBl[lr][ls + 8] = bl1;
    __syncthreads();
    int ra = wr + (lane & 15), rb = wc + (lane & 15), kk = (lane >> 4) * 8;
    bf16x8 ah[4], al[4], bh[4], bl[4];
#pragma unroll
    for (int q = 0; q < 4; ++q) {
      ah[q] = *(const bf16x8*)&sAh[ra + q * 16][kk];
      al[q] = *(const bf16x8*)&sAl[ra + q * 16][kk];
      bh[q] = *(const bf16x8*)&sBh[rb + q * 16][kk];
      bl[q] = *(const bf16x8*)&sBl[rb + q * 16][kk];
    }
#pragma unroll
    for (int mt = 0; mt < 4; ++mt)
#pragma unroll
      for (int nt = 0; nt < 4; ++nt) {
        acc[mt][nt] = __builtin_amdgcn_mfma_f32_16x16x32_bf16(ah[mt], bh[nt], acc[mt][nt], 0, 0, 0);
        acc[mt][nt] = __builtin_amdgcn_mfma_f32_16x16x32_bf16(ah[mt], bl[nt], acc[mt][nt], 0, 0, 0);
        acc[mt][nt] = __builtin_amdgcn_mfma_f32_16x16x32_bf16(al[mt], bh[nt], acc[mt][nt], 0, 0, 0);
      }
  }
  int colb = n0 + wc + (lane & 15);
#pragma unroll
  for (int mt = 0; mt < 4; ++mt) {
#pragma unroll
    for (int nt = 0; nt < 4; ++nt) {
#pragma unroll
      for (int jq = 0; jq < 4; ++jq) {
        int row = m0 + wr + mt * 16 + (lane >> 4) * 4 + jq;
        int cc = colb + nt * 16;
        float v = acc[mt][nt][jq];
        if (EPI == 0) C[(size_t)row * N + cc] = v;
        else C[(size_t)row * N + cc] = v * sigf(v);
      }
    }
  }
}

// ---------------- split-bf16 MFMA GEMM, A pre-split (final o) ----------------
__global__ __launch_bounds__(256) void gemm_ps_kernel(const ushort* __restrict__ Ah,
                                                      const ushort* __restrict__ Al,
                                                      const ushort* __restrict__ BTh,
                                                      const ushort* __restrict__ BTl,
                                                      float* __restrict__ C, int M, int N) {
  __shared__ ushort sAh[128][40];
  __shared__ ushort sAl[128][40];
  __shared__ ushort sBh[128][40];
  __shared__ ushort sBl[128][40];
  const int K = 1024;
  int m0 = blockIdx.x * 128, n0 = blockIdx.y * 128;
  int tid = threadIdx.x;
  int w = tid >> 6, lane = tid & 63;
  int wr = (w >> 1) * 64, wc = (w & 1) * 64;
  f32x4 acc[4][4];
#pragma unroll
  for (int i = 0; i < 4; ++i)
#pragma unroll
    for (int jq = 0; jq < 4; ++jq) acc[i][jq] = (f32x4){0.f, 0.f, 0.f, 0.f};
  int lr = tid >> 1, ls = (tid & 1) * 16;
  const ushort* gah = Ah + (size_t)(m0 + lr) * K + ls;
  const ushort* gal = Al + (size_t)(m0 + lr) * K + ls;
  const ushort* gbh = BTh + (size_t)(n0 + lr) * K + ls;
  const ushort* gbl = BTl + (size_t)(n0 + lr) * K + ls;
  for (int k0 = 0; k0 < K; k0 += 32) {
    uint4 ah0 = *(const uint4*)(gah + k0);
    uint4 ah1 = *(const uint4*)(gah + k0 + 8);
    uint4 al0 = *(const uint4*)(gal + k0);
    uint4 al1 = *(const uint4*)(gal + k0 + 8);
    uint4 bh0 = *(const uint4*)(gbh + k0);
    uint4 bh1 = *(const uint4*)(gbh + k0 + 8);
    uint4 bl0 = *(const uint4*)(gbl + k0);
    uint4 bl1 = *(const uint4*)(gbl + k0 + 8);
    __syncthreads();
    *(uint4*)&sAh[lr][ls] = ah0; *(uint4*)&sAh[lr][ls + 8] = ah1;
    *(uint4*)&sAl[lr][ls] = al0; *(uint4*)&sAl[lr][ls + 8] = al1;
    *(uint4*)&sBh[lr][ls] = bh0; *(uint4*)&sBh[lr][ls + 8] = bh1;
    *(uint4*)&sBl[lr][ls] = bl0; *(uint4*)&sBl[lr][ls + 8] = bl1;
    __syncthreads();
    int ra = wr + (lane & 15), rb = wc + (lane & 15), kk = (lane >> 4) * 8;
    bf16x8 ah[4], al[4], bh[4], bl[4];
#pragma unroll
    for (int q = 0; q < 4; ++q) {
      ah[q] = *(const bf16x8*)&sAh[ra + q * 16][kk];
      al[q] = *(const bf16x8*)&sAl[ra + q * 16][kk];
      bh[q] = *(const bf16x8*)&sBh[rb + q * 16][kk];
      bl[q] = *(const bf16x8*)&sBl[rb + q * 16][kk];
    }
#pragma unroll
    for (int mt = 0; mt < 4; ++mt)
#pragma unroll
      for (int nt = 0; nt < 4; ++nt) {
        acc[mt][nt] = __builtin_amdgcn_mfma_f32_16x16x32_bf16(ah[mt], bh[nt], acc[mt][nt], 0, 0, 0);
        acc[mt][nt] = __builtin_amdgcn_mfma_f32_16x16x32_bf16(ah[mt], bl[nt], acc[mt][nt], 0, 0, 0);
        acc[mt][nt] = __builtin_amdgcn_mfma_f32_16x16x32_bf16(al[mt], bh[nt], acc[mt][nt], 0, 0, 0);
      }
  }
  int colb = n0 + wc + (lane & 15);
#pragma unroll
  for (int mt = 0; mt < 4; ++mt) {
#pragma unroll
    for (int nt = 0; nt < 4; ++nt) {
#pragma unroll
      for (int jq = 0; jq < 4; ++jq) {
        int row = m0 + wr + mt * 16 + (lane >> 4) * 4 + jq;
        int cc = colb + nt * 16;
        C[(size_t)row * N + cc] = acc[mt][nt][jq];
      }
    }
  }
}

// ---------------- fused q/k/v projection GEMMs (blockIdx.z selects weight) ----------------
__global__ __launch_bounds__(256) void gemm_ps3_kernel(const ushort* __restrict__ Ah,
                                                       const ushort* __restrict__ Al,
                                                       const ushort* __restrict__ B0h,
                                                       const ushort* __restrict__ B0l,
                                                       const ushort* __restrict__ B1h,
                                                       const ushort* __restrict__ B1l,
                                                       const ushort* __restrict__ B2h,
                                                       const ushort* __restrict__ B2l,
                                                       float* __restrict__ C, int M, int N) {
  __shared__ ushort sAh[128][40];
  __shared__ ushort sAl[128][40];
  __shared__ ushort sBh[128][40];
  __shared__ ushort sBl[128][40];
  const int K = 1024;
  int zz = blockIdx.z;
  const ushort* BTh = (zz == 0) ? B0h : (zz == 1) ? B1h : B2h;
  const ushort* BTl = (zz == 0) ? B0l : (zz == 1) ? B1l : B2l;
  float* Cz = C + (size_t)zz * M * N;
  int m0 = blockIdx.x * 128, n0 = blockIdx.y * 128;
  int tid = threadIdx.x;
  int w = tid >> 6, lane = tid & 63;
  int wr = (w >> 1) * 64, wc = (w & 1) * 64;
  f32x4 acc[4][4];
#pragma unroll
  for (int i = 0; i < 4; ++i)
#pragma unroll
    for (int jq = 0; jq < 4; ++jq) acc[i][jq] = (f32x4){0.f, 0.f, 0.f, 0.f};
  int lr = tid >> 1, ls = (tid & 1) * 16;
  const ushort* gah = Ah + (size_t)(m0 + lr) * K + ls;
  const ushort* gal = Al + (size_t)(m0 + lr) * K + ls;
  const ushort* gbh = BTh + (size_t)(n0 + lr) * K + ls;
  const ushort* gbl = BTl + (size_t)(n0 + lr) * K + ls;
  for (int k0 = 0; k0 < K; k0 += 32) {
    uint4 ah0 = *(const uint4*)(gah + k0);
    uint4 ah1 = *(const uint4*)(gah + k0 + 8);
    uint4 al0 = *(const uint4*)(gal + k0);
    uint4 al1 = *(const uint4*)(gal + k0 + 8);
    uint4 bh0 = *(const uint4*)(gbh + k0);
    uint4 bh1 = *(const uint4*)(gbh + k0 + 8);
    uint4 bl0 = *(const uint4*)(gbl + k0);
    uint4 bl1 = *(const uint4*)(gbl + k0 + 8);
    __syncthreads();
    *(uint4*)&sAh[lr][ls] = ah0; *(uint4*)&sAh[lr][ls + 8] = ah1;
    *(uint4*)&sAl[lr][ls] = al0; *(uint4*)&sAl[lr][ls + 8] = al1;
    *(uint4*)&sBh[lr][ls] = bh0; *(uint4*)&sBh[lr][ls + 8] = bh1;
    *(uint4*)&sBl[lr][ls] = bl0; *(uint4*)&sBl[lr][ls + 8] = bl1;
    __syncthreads();
    int ra = wr + (lane & 15), rb = wc + (lane & 15), kk = (lane >> 4) * 8;
    bf16x8 ah[4], al[4], bh[4], bl[4];
#pragma unroll
    for (int q = 0; q < 4; ++q) {
      ah[q] = *(const bf16x8*)&sAh[ra + q * 16][kk];
      al[q] = *(const bf16x8*)&sAl[ra + q * 16][kk];
      bh[q] = *(const bf16x8*)&sBh[rb + q * 16][kk];
      bl[q] = *(const bf16x8*)&sBl[rb + q * 16][kk];
    }
#pragma unroll
    for (int mt = 0; mt < 4; ++mt)
#pragma unroll
      for (int nt = 0; nt < 4; ++nt) {
        acc[mt][nt] = __builtin_amdgcn_mfma_f32_16x16x32_bf16(ah[mt], bh[nt], acc[mt][nt], 0, 0, 0);
        acc[mt][nt] = __builtin_amdgcn_mfma_f32_16x16x32_bf16(ah[mt], bl[nt], acc[mt][nt], 0, 0, 0);
        acc[mt][nt] = __builtin_amdgcn_mfma_f32_16x16x32_bf16(al[mt], bh[nt], acc[mt][nt], 0, 0, 0);
      }
  }
  int colb = n0 + wc + (lane & 15);
#pragma unroll
  for (int mt = 0; mt < 4; ++mt) {
#pragma unroll
    for (int nt = 0; nt < 4; ++nt) {
#pragma unroll
      for (int jq = 0; jq < 4; ++jq) {
        int row = m0 + wr + mt * 16 + (lane >> 4) * 4 + jq;
        int cc = colb + nt * 16;
        Cz[(size_t)row * N + cc] = acc[mt][nt][jq];
      }
    }
  }
}

// ---------------- merged depthwise conv(4)+silu(+l2norm+rope) for q,k,v of one b ----------------
__global__ void conv3_kernel(const float* __restrict__ lin3, const float* __restrict__ cwq,
                             const float* __restrict__ cbq, const float* __restrict__ cwk,
                             const float* __restrict__ cbk, const float* __restrict__ cwv,
                             const float* __restrict__ cbv, const float* __restrict__ cosT,
                             const float* __restrict__ sinT, float* __restrict__ qh,
                             float* __restrict__ kh, float* __restrict__ vh, int b) {
  int u = blockIdx.x * 4 + (threadIdx.x >> 6);  // [0, 3*32768)
  int which = u >> 15;
  int uu = u & 32767;
  int lane = threadIdx.x & 63;
  int h = uu >> 12, t = uu & 4095;
  int c0 = h * 128 + lane;
  const float* lin = lin3 + (size_t)which * 4096 * 1024;
  const float* cw = (which == 0) ? cwq : (which == 1) ? cwk : cwv;
  const float* cb = (which == 0) ? cbq : (which == 1) ? cbk : cbv;
  float* outp = (which == 0) ? qh : (which == 1) ? kh : vh;
  float4 w0 = *(const float4*)&cw[(size_t)c0 * 4];
  float4 w1 = *(const float4*)&cw[(size_t)(c0 + 64) * 4];
  float w0a[4] = {w0.x, w0.y, w0.z, w0.w};
  float w1a[4] = {w1.x, w1.y, w1.z, w1.w};
  float y0 = cb[c0], y1 = cb[c0 + 64];
  const float* base = lin + c0;
#pragma unroll
  for (int j = 0; j < 4; ++j) {
    int tj = t - 3 + j;
    if (tj >= 0) {
      y0 += w0a[j] * base[(size_t)tj * 1024];
      y1 += w1a[j] * base[(size_t)tj * 1024 + 64];
    }
  }
  y0 = y0 * sigf(y0);
  y1 = y1 * sigf(y1);
  if (which < 2) {
    float ss = y0 * y0 + y1 * y1;
#pragma unroll
    for (int off = 1; off < 64; off <<= 1) ss += __shfl_xor(ss, off);
    float sc = 1.f / fmaxf(sqrtf(ss), 1e-12f);
    y0 *= sc; y1 *= sc;
    float cv = cosT[t * 64 + lane], sv = sinT[t * 64 + lane];
    float o0 = y0 * cv - y1 * sv;
    float o1 = y1 * cv + y0 * sv;
    y0 = o0; y1 = o1;
  }
  int p = b * 8 + h;
  float* dst = outp + (((size_t)p * 64 + (t >> 6)) * 64 + (t & 63)) * 128;
  dst[lane] = y0;
  dst[lane + 64] = y1;
}

// ---------------- pair-local sync ----------------
__device__ __forceinline__ void pair_sync(unsigned* ctr, unsigned target) {
  asm volatile("s_waitcnt vmcnt(0)" ::: "memory");
  __syncthreads();
  if (threadIdx.x == 0) {
    __hip_atomic_fetch_add(ctr, 1u, __ATOMIC_RELAXED, __HIP_MEMORY_SCOPE_AGENT);
    int spins = 0;
    while (__hip_atomic_load(ctr, __ATOMIC_RELAXED, __HIP_MEMORY_SCOPE_AGENT) < target) {
      __builtin_amdgcn_s_sleep(4);
      if (++spins > (1 << 18)) break;
    }
  }
  __syncthreads();
}
__device__ __forceinline__ double wredd(double v) {
#pragma unroll
  for (int off = 1; off < 64; off <<= 1) v += __shfl_xor(v, off);
  return v;
}

// ---------------- the chunked TTT scan (round-10 structure, SPAD=129) ----------------
__global__ __launch_bounds__(512, 2) void scan_kernel(
    const float* qh, const float* __restrict__ kh, const float* __restrict__ vh,
    const float* __restrict__ theta, const float* __restrict__ etab, const float* __restrict__ alpb,
    const float* __restrict__ W1i, const float* __restrict__ W2i,
    const float* __restrict__ gmm, const float* __restrict__ btt,
    float* __restrict__ pslots, float* __restrict__ oslots, float* __restrict__ zslots,
    float* obuf, unsigned* __restrict__ bar) {
  extern __shared__ float lds[];
  float* sW1 = lds;                  // [32][SPAD]
  float* sW2 = sW1 + 32 * SPAD;      // [32][SPAD]
  float* sK = sW2 + 32 * SPAD;       // [64][SPAD]
  float* sZ = sK + 64 * SPAD;        // [64][SPAD]
  float* sA = sZ + 64 * SPAD;        // [64][APAD]

  int wg = blockIdx.x;
  int xcd = wg & 7, jj0 = wg >> 3;
  int p = xcd * 4 + (jj0 >> 3), mb = jj0 & 7;
  int b = p >> 3, hh = p & 7;
  int m0 = mb * 32;
  int tid = threadIdx.x;
  unsigned* ctr = bar + (size_t)p * 64;

  for (int it = 0; it < 8; ++it) {
    int e = tid + it * 512;
    int m = e & 31, d = e >> 5;
    sW1[m * SPAD + d] = W1i[((size_t)hh * 128 + d) * 256 + m0 + m];
    sW2[m * SPAD + d] = W2i[((size_t)hh * 256 + m0 + m) * 128 + d];
  }
  float rS1[8], rS2[8];
#pragma unroll
  for (int e = 0; e < 8; ++e) { rS1[e] = 0.f; rS2[e] = 0.f; }

  const float* khp = kh + (size_t)p * (64 * 64 * 128);
  const float* qhp = qh + (size_t)p * (64 * 64 * 128);
  const float* vhp = vh + (size_t)p * (64 * 64 * 128);

  int tm = tid & 31, ti = tid >> 5;
  int i0 = ti * 4;
  int d0p = tm * 4;
  int dg = ti * 8;

  int wid = tid >> 6, lane = tid & 63;
  int rw = mb * 8 + wid;
  int dl = lane * 2;
  float g0 = gmm[hh * 128 + dl], g1 = gmm[hh * 128 + dl + 1];
  float b0 = btt[hh * 128 + dl], b1 = btt[hh * 128 + dl + 1];

  float hreg[4];
  __syncthreads();

  for (int c = 0; c < 64; ++c) {
    // ---- P1: load K+Q tiles to regs (nt), stage K to LDS, hold Q ----
    f32x4 qreg[4];
    {
      const float* srcK = khp + (size_t)c * 8192;
      const float* srcQ = qhp + (size_t)c * 8192;
      f32x4 kreg[4];
#pragma unroll
      for (int it = 0; it < 4; ++it) {
        int e = tid * 4 + it * 2048;
        kreg[it] = __builtin_nontemporal_load((const f32x4*)&srcK[e]);
        qreg[it] = __builtin_nontemporal_load((const f32x4*)&srcQ[e]);
      }
#pragma unroll
      for (int it = 0; it < 4; ++it) {
        int e = tid * 4 + it * 2048;
        *(f32x4*)&sK[(e >> 7) * SPAD + (e & 127)] = kreg[it];
      }
    }
    __syncthreads();
    // h = k@W1block ; a = silu(h)
    {
      float acc[4] = {0.f, 0.f, 0.f, 0.f};
      for (int d = 0; d < 128; d += 16) {
        float4 wv[4], kv4[4][4];
#pragma unroll
        for (int q = 0; q < 4; ++q) wv[q] = *(const float4*)&sW1[tm * SPAD + d + 4 * q];
#pragma unroll
        for (int r = 0; r < 4; ++r)
#pragma unroll
          for (int q = 0; q < 4; ++q) kv4[r][q] = *(const float4*)&sK[(i0 + r) * SPAD + d + 4 * q];
#pragma unroll
        for (int q = 0; q < 4; ++q)
#pragma unroll
          for (int r = 0; r < 4; ++r)
            acc[r] += kv4[r][q].x * wv[q].x + kv4[r][q].y * wv[q].y +
                      kv4[r][q].z * wv[q].z + kv4[r][q].w * wv[q].w;
      }
#pragma unroll
      for (int r = 0; r < 4; ++r) {
        hreg[r] = acc[r];
        sA[(i0 + r) * APAD + tm] = acc[r] * sigf(acc[r]);
      }
    }
    __syncthreads();
    // pred partial = a(:,block) @ W2block -> slot (plain stores -> own-XCD L2)
    {
      float pacc[4][4] = {{0.f}};
      for (int m = 0; m < 32; m += 8) {
        float4 wv[8];
        float av[4][8];
#pragma unroll
        for (int mm = 0; mm < 8; ++mm) wv[mm] = *(const float4*)&sW2[(m + mm) * SPAD + d0p];
#pragma unroll
        for (int r = 0; r < 4; ++r)
#pragma unroll
          for (int mm = 0; mm < 8; ++mm) av[r][mm] = sA[(i0 + r) * APAD + m + mm];
#pragma unroll
        for (int mm = 0; mm < 8; ++mm)
#pragma unroll
          for (int r = 0; r < 4; ++r) {
            pacc[r][0] += av[r][mm] * wv[mm].x; pacc[r][1] += av[r][mm] * wv[mm].y;
            pacc[r][2] += av[r][mm] * wv[mm].z; pacc[r][3] += av[r][mm] * wv[mm].w;
          }
      }
      float* ps = pslots + (((size_t)(c & 1) * 32 + p) * 8 + mb) * 8192;
#pragma unroll
      for (int r = 0; r < 4; ++r)
        *(float4*)&ps[(i0 + r) * 128 + d0p] =
            make_float4(pacc[r][0], pacc[r][1], pacc[r][2], pacc[r][3]);
    }
    pair_sync(ctr, 16u * c + 8u);
    // ---- P2: distributed pred-reduce + fp64 LN-l2-bwd for own 8 rows; z -> slot ----
    {
      f32x2 ot[8];
      if (c > 0) {
        const float* ob =
            oslots + ((size_t)((c - 1) & 1) * 32 + p) * 8 * 8192 + rw * 128 + dl;
        scload8(ob, ot);
      }
      const float* pb = pslots + ((size_t)(c & 1) * 32 + p) * 8 * 8192 + rw * 128 + dl;
      f32x2 pt[8];
      scload8(pb, pt);
      f32x2 vld = __builtin_nontemporal_load((const f32x2*)&vhp[(size_t)c * 8192 + rw * 128 + dl]);
      float pr0 = 0.f, pr1 = 0.f;
#pragma unroll
      for (int m2 = 0; m2 < 8; ++m2) { pr0 += pt[m2][0]; pr1 += pt[m2][1]; }
      double s = (double)pr0 + (double)pr1;
      s = wredd(s);
      double mu = s * (1.0 / 128.0);
      double dd0 = (double)pr0 - mu, dd1 = (double)pr1 - mu;
      double vp = wredd(dd0 * dd0 + dd1 * dd1);
      double rstd = 1.0 / sqrt(vp * (1.0 / 128.0) + (double)EPSF);
      double xh0 = dd0 * rstd, xh1 = dd1 * rstd;
      double gxh0 = 2.0 * (((double)g0 * xh0 + (double)b0) - (double)vld[0]) * (double)g0;
      double gxh1 = 2.0 * (((double)g1 * xh1 + (double)b1) - (double)vld[1]) * (double)g1;
      double s1 = wredd(gxh0 + gxh1);
      double s2 = wredd(gxh0 * xh0 + gxh1 * xh1);
      float th = theta[((size_t)b * 4096 + c * 64 + rw) * 8 + hh];
      double zsc = rstd * (1.0 / 128.0) * (double)th;
      float z0 = (float)((128.0 * gxh0 - s1 - xh0 * s2) * zsc);
      float z1 = (float)((128.0 * gxh1 - s1 - xh1 * s2) * zsc);
      float* zs = zslots + ((size_t)(c & 1) * 32 + p) * 8192;
      *(f32x2*)&zs[rw * 128 + dl] = (f32x2){z0, z1};
      if (c > 0) {
        float o0 = 0.f, o1 = 0.f;
#pragma unroll
        for (int m2 = 0; m2 < 8; ++m2) { o0 += ot[m2][0]; o1 += ot[m2][1]; }
        __builtin_nontemporal_store(
            (f32x2){o0, o1},
            (f32x2*)&obuf[(((size_t)p * 64 + (c - 1)) * 64 + rw) * 128 + dl]);
      }
    }
    pair_sync(ctr, 16u * c + 16u);
    // ---- P3: read full z -> sZ (sc0 loads) ----
    {
      int zr = tid >> 3, zc = (tid & 7) * 16;
      const float* zb = zslots + ((size_t)(c & 1) * 32 + p) * 8192 + zr * 128 + zc;
      f32x4 zt[4];
      scload4(zb, zt);
#pragma unroll
      for (int j = 0; j < 4; ++j) *(f32x4*)&sZ[zr * SPAD + zc + 4 * j] = zt[j];
    }
    __syncthreads();
    // gW2 = a^T z  (own m rows)
    float gw2[8];
    {
#pragma unroll
      for (int e = 0; e < 8; ++e) gw2[e] = 0.f;
      for (int i = 0; i < 64; i += 8) {
        float av[8];
        float4 z0[8], z1[8];
#pragma unroll
        for (int ii = 0; ii < 8; ++ii) av[ii] = sA[(i + ii) * APAD + tm];
#pragma unroll
        for (int ii = 0; ii < 8; ++ii) {
          z0[ii] = *(const float4*)&sZ[(i + ii) * SPAD + dg];
          z1[ii] = *(const float4*)&sZ[(i + ii) * SPAD + dg + 4];
        }
#pragma unroll
        for (int ii = 0; ii < 8; ++ii) {
          gw2[0] += av[ii] * z0[ii].x; gw2[1] += av[ii] * z0[ii].y;
          gw2[2] += av[ii] * z0[ii].z; gw2[3] += av[ii] * z0[ii].w;
          gw2[4] += av[ii] * z1[ii].x; gw2[5] += av[ii] * z1[ii].y;
          gw2[6] += av[ii] * z1[ii].z; gw2[7] += av[ii] * z1[ii].w;
        }
      }
    }
    // gh = (z @ W2block^T) * silu'(h)
    float ghr[4];
    {
      float acc[4] = {0.f, 0.f, 0.f, 0.f};
      for (int d = 0; d < 128; d += 16) {
        float4 wv[4], zv4[4][4];
#pragma unroll
        for (int q = 0; q < 4; ++q) wv[q] = *(const float4*)&sW2[tm * SPAD + d + 4 * q];
#pragma unroll
        for (int r = 0; r < 4; ++r)
#pragma unroll
          for (int q = 0; q < 4; ++q) zv4[r][q] = *(const float4*)&sZ[(i0 + r) * SPAD + d + 4 * q];
#pragma unroll
        for (int q = 0; q < 4; ++q)
#pragma unroll
          for (int r = 0; r < 4; ++r)
            acc[r] += zv4[r][q].x * wv[q].x + zv4[r][q].y * wv[q].y +
                      zv4[r][q].z * wv[q].z + zv4[r][q].w * wv[q].w;
      }
#pragma unroll
      for (int r = 0; r < 4; ++r) {
        float hv = hreg[r];
        float sg = sigf(hv);
        ghr[r] = acc[r] * (sg + hv * sg * (1.f - sg));
      }
    }
    __syncthreads();
#pragma unroll
    for (int r = 0; r < 4; ++r) sA[(i0 + r) * APAD + tm] = ghr[r];
    __syncthreads();
    // gW1 = k^T gh  (own m cols) ; state update (S in regs)
    {
      float gw1[8];
#pragma unroll
      for (int e = 0; e < 8; ++e) gw1[e] = 0.f;
      for (int i = 0; i < 64; i += 8) {
        float gvv[8];
        float4 k0[8], k1[8];
#pragma unroll
        for (int ii = 0; ii < 8; ++ii) gvv[ii] = sA[(i + ii) * APAD + tm];
#pragma unroll
        for (int ii = 0; ii < 8; ++ii) {
          k0[ii] = *(const float4*)&sK[(i + ii) * SPAD + dg];
          k1[ii] = *(const float4*)&sK[(i + ii) * SPAD + dg + 4];
        }
#pragma unroll
        for (int ii = 0; ii < 8; ++ii) {
          gw1[0] += gvv[ii] * k0[ii].x; gw1[1] += gvv[ii] * k0[ii].y;
          gw1[2] += gvv[ii] * k0[ii].z; gw1[3] += gvv[ii] * k0[ii].w;
          gw1[4] += gvv[ii] * k1[ii].x; gw1[5] += gvv[ii] * k1[ii].y;
          gw1[6] += gvv[ii] * k1[ii].z; gw1[7] += gvv[ii] * k1[ii].w;
        }
      }
      float ei = etab[((size_t)b * 4096 + c * 64 + 63) * 8 + hh];
      float ai = alpb[((size_t)b * 4096 + c * 64 + 63) * 8 + hh];
      float om = 1.f - ai;
#pragma unroll
      for (int g2 = 0; g2 < 2; ++g2) {
        int dd = dg + g2 * 4;
#pragma unroll
        for (int j = 0; j < 4; ++j) rS1[g2 * 4 + j] = ei * rS1[g2 * 4 + j] - gw1[g2 * 4 + j];
        float4 w1v = *(const float4*)&sW1[tm * SPAD + dd];
        w1v.x = om * w1v.x + rS1[g2 * 4 + 0]; w1v.y = om * w1v.y + rS1[g2 * 4 + 1];
        w1v.z = om * w1v.z + rS1[g2 * 4 + 2]; w1v.w = om * w1v.w + rS1[g2 * 4 + 3];
        *(float4*)&sW1[tm * SPAD + dd] = w1v;
#pragma unroll
        for (int j = 0; j < 4; ++j) rS2[g2 * 4 + j] = ei * rS2[g2 * 4 + j] - gw2[g2 * 4 + j];
        float4 w2v = *(const float4*)&sW2[tm * SPAD + dd];
        w2v.x = om * w2v.x + rS2[g2 * 4 + 0]; w2v.y = om * w2v.y + rS2[g2 * 4 + 1];
        w2v.z = om * w2v.z + rS2[g2 * 4 + 2]; w2v.w = om * w2v.w + rS2[g2 * 4 + 3];
        *(float4*)&sW2[tm * SPAD + dd] = w2v;
      }
    }
    __syncthreads();
    // stage Q tile into sK (from regs)
    {
#pragma unroll
      for (int it = 0; it < 4; ++it) {
        int e = tid * 4 + it * 2048;
        *(f32x4*)&sK[(e >> 7) * SPAD + (e & 127)] = qreg[it];
      }
    }
    __syncthreads();
    // a_o = silu(q @ W1new)
    {
      float acc[4] = {0.f, 0.f, 0.f, 0.f};
      for (int d = 0; d < 128; d += 16) {
        float4 wv[4], kv4[4][4];
#pragma unroll
        for (int q = 0; q < 4; ++q) wv[q] = *(const float4*)&sW1[tm * SPAD + d + 4 * q];
#pragma unroll
        for (int r = 0; r < 4; ++r)
#pragma unroll
          for (int q = 0; q < 4; ++q) kv4[r][q] = *(const float4*)&sK[(i0 + r) * SPAD + d + 4 * q];
#pragma unroll
        for (int q = 0; q < 4; ++q)
#pragma unroll
          for (int r = 0; r < 4; ++r)
            acc[r] += kv4[r][q].x * wv[q].x + kv4[r][q].y * wv[q].y +
                      kv4[r][q].z * wv[q].z + kv4[r][q].w * wv[q].w;
      }
#pragma unroll
      for (int r = 0; r < 4; ++r) sA[(i0 + r) * APAD + tm] = acc[r] * sigf(acc[r]);
    }
    __syncthreads();
    // o partial = a_o @ W2new -> slot (plain stores)
    {
      float oacc[4][4] = {{0.f}};
      for (int m = 0; m < 32; m += 8) {
        float4 wv[8];
        float av[4][8];
#pragma unroll
        for (int mm = 0; mm < 8; ++mm) wv[mm] = *(const float4*)&sW2[(m + mm) * SPAD + d0p];
#pragma unroll
        for (int r = 0; r < 4; ++r)
#pragma unroll
          for (int mm = 0; mm < 8; ++mm) av[r][mm] = sA[(i0 + r) * APAD + m + mm];
#pragma unroll
        for (int mm = 0; mm < 8; ++mm)
#pragma unroll
          for (int r = 0; r < 4; ++r) {
            oacc[r][0] += av[r][mm] * wv[mm].x; oacc[r][1] += av[r][mm] * wv[mm].y;
            oacc[r][2] += av[r][mm] * wv[mm].z; oacc[r][3] += av[r][mm] * wv[mm].w;
          }
      }
      float* os = oslots + (((size_t)(c & 1) * 32 + p) * 8 + mb) * 8192;
#pragma unroll
      for (int r = 0; r < 4; ++r)
        *(float4*)&os[(i0 + r) * 128 + d0p] =
            make_float4(oacc[r][0], oacc[r][1], oacc[r][2], oacc[r][3]);
    }
  }
  // tail: reduce o of chunk 63
  pair_sync(ctr, 16u * 64 + 8u);
  {
    const float* ob = oslots + ((size_t)(63 & 1) * 32 + p) * 8 * 8192 + rw * 128 + dl;
    f32x2 t[8];
    scload8(ob, t);
    float o0 = 0.f, o1 = 0.f;
#pragma unroll
    for (int m2 = 0; m2 < 8; ++m2) { o0 += t[m2][0]; o1 += t[m2][1]; }
    *(f32x2*)&obuf[(((size_t)p * 64 + 63) * 64 + rw) * 128 + dl] = (f32x2){o0, o1};
  }
}

// ---------------- head LN + l2norm + gate -> bf16 hi/lo y ----------------
__global__ __launch_bounds__(256) void post_kernel(const float* __restrict__ obuf,
                                                   const float* __restrict__ gate,
                                                   const float* __restrict__ gmm,
                                                   const float* __restrict__ btt,
                                                   ushort* __restrict__ yh,
                                                   ushort* __restrict__ yl) {
  __shared__ float red[4];
  int row = blockIdx.x;
  int tid = threadIdx.x;
  int ch = tid * 4;
  int h = tid >> 5;
  int bb = row >> 12, t = row & 4095;
  int p = bb * 8 + h, cc = t >> 6, rr = t & 63;
  int dloc = (tid & 31) * 4;
  float4 o = *(const float4*)&obuf[(((size_t)p * 64 + cc) * 64 + rr) * 128 + dloc];
  float s = o.x + o.y + o.z + o.w;
#pragma unroll
  for (int off = 1; off < 32; off <<= 1) s += __shfl_xor(s, off);
  float mu = s * (1.f / 128.f);
  float dx = o.x - mu, dy = o.y - mu, dz = o.z - mu, dw = o.w - mu;
  float vp = dx * dx + dy * dy + dz * dz + dw * dw;
#pragma unroll
  for (int off = 1; off < 32; off <<= 1) vp += __shfl_xor(vp, off);
  float rstd = 1.f / sqrtf(vp * (1.f / 128.f) + EPSF);
  float4 g4 = *(const float4*)&gmm[h * 128 + dloc];
  float4 b4 = *(const float4*)&btt[h * 128 + dloc];
  float y0 = g4.x * (dx * rstd) + b4.x;
  float y1 = g4.y * (dy * rstd) + b4.y;
  float y2 = g4.z * (dz * rstd) + b4.z;
  float y3 = g4.w * (dw * rstd) + b4.w;
  float ss = y0 * y0 + y1 * y1 + y2 * y2 + y3 * y3;
#pragma unroll
  for (int off = 1; off < 64; off <<= 1) ss += __shfl_xor(ss, off);
  if ((tid & 63) == 0) red[tid >> 6] = ss;
  __syncthreads();
  float tot = red[0] + red[1] + red[2] + red[3];
  float sc = 1.f / fmaxf(sqrtf(tot), 1e-12f);
  float4 gt = *(const float4*)&gate[(size_t)row * 1024 + ch];
  float yv[4] = {y0 * sc * gt.x, y1 * sc * gt.y, y2 * sc * gt.z, y3 * sc * gt.w};
  ushort hh[4], ll[4];
#pragma unroll
  for (int q = 0; q < 4; ++q) {
    hh[q] = f2bf(yv[q]);
    ll[q] = f2bf(yv[q] - bf2f(hh[q]));
  }
  *(ushort4*)&yh[(size_t)row * 1024 + ch] = make_ushort4(hh[0], hh[1], hh[2], hh[3]);
  *(ushort4*)&yl[(size_t)row * 1024 + ch] = make_ushort4(ll[0], ll[1], ll[2], ll[3]);
}

// ---------------- host ----------------
extern "C" void kernel_launch(void* const* d_in, const int* in_sizes, int n_in, void* d_out,
                              int out_size, void* d_ws, size_t ws_size, hipStream_t stream) {
  const float* x = (const float*)d_in[0];
  const float* Wq = (const float*)d_in[1];
  const float* Wk = (const float*)d_in[2];
  const float* Wv = (const float*)d_in[3];
  const float* cwq = (const float*)d_in[4];
  const float* cbq = (const float*)d_in[5];
  const float* cwk = (const float*)d_in[6];
  const float* cbk = (const float*)d_in[7];
  const float* cwv = (const float*)d_in[8];
  const float* cbv = (const float*)d_in[9];
  const float* Wal = (const float*)d_in[10];
  const float* Wet = (const float*)d_in[11];
  const float* Wth = (const float*)d_in[12];
  const float* W1i = (const float*)d_in[13];
  const float* W2i = (const float*)d_in[14];
  const float* gmm = (const float*)d_in[15];
  const float* btt = (const float*)d_in[16];
  const float* gW = (const float*)d_in[17];
  const float* oW = (const float*)d_in[18];

  char* ws = (char*)d_ws;
  size_t off = 0;
  auto alloc = [&](size_t bytes) {
    void* pp = ws + off;
    off += (bytes + 255) & ~(size_t)255;
    return pp;
  };
  const size_t MTOT = 16384ull;
  unsigned* bar = (unsigned*)alloc(32 * 64 * 4);
  float* alpb = (float*)alloc(MTOT * 8 * 4);
  float* etab = (float*)alloc(MTOT * 8 * 4);
  float* thetab = (float*)alloc(MTOT * 8 * 4);
  float* cosT = (float*)alloc(4096ull * 64 * 4);
  float* sinT = (float*)alloc(4096ull * 64 * 4);
  ushort* wtqh = (ushort*)alloc(1024ull * 1024 * 2);
  ushort* wtql = (ushort*)alloc(1024ull * 1024 * 2);
  ushort* wtkh = (ushort*)alloc(1024ull * 1024 * 2);
  ushort* wtkl = (ushort*)alloc(1024ull * 1024 * 2);
  ushort* wtvh = (ushort*)alloc(1024ull * 1024 * 2);
  ushort* wtvl = (ushort*)alloc(1024ull * 1024 * 2);
  ushort* wtgh = (ushort*)alloc(1024ull * 1024 * 2);
  ushort* wtgl = (ushort*)alloc(1024ull * 1024 * 2);
  ushort* wtoh = (ushort*)alloc(1024ull * 1024 * 2);
  ushort* wtol = (ushort*)alloc(1024ull * 1024 * 2);
  float* qh = (float*)alloc(MTOT * 1024 * 4);     // fp32 q; obuf overlays after use
  float* kh = (float*)alloc(MTOT * 1024 * 4);     // fp32 k; yh/yl overlay after scan
  float* vh = (float*)alloc(MTOT * 1024 * 4);     // fp32 v; gate overlays after scan
  ushort* xbh = (ushort*)alloc(4096ull * 1024 * 2);  // per-b pre-split x hi
  ushort* xbl = (ushort*)alloc(4096ull * 1024 * 2);  // per-b pre-split x lo

  // d_out time-multiplexed: [lin_q|lin_k|lin_v] (proj, 50.4MB); [p|o|z slots x2] (scan, 34MB)
  float* lin3 = (float*)d_out;
  float* pslots = (float*)d_out;
  float* oslots = pslots + 2ull * 32 * 8 * 8192;
  float* zslots = oslots + 2ull * 32 * 8 * 8192;
  float* obuf = qh;
  float* gate = vh;
  ushort* yh = (ushort*)kh;
  ushort* yl = yh + MTOT * 1024;

  dim3 tg5(16, 16, 5);
  cvt_wT_split5_kernel<<<tg5, 256, 0, stream>>>(Wq, Wk, Wv, gW, oW, wtqh, wtql, wtkh, wtkl, wtvh,
                                                wtvl, wtgh, wtgl, wtoh, wtol);
  rope_table_kernel<<<4096, 64, 0, stream>>>(cosT, sinT);
  proj_small_kernel<<<64, 256, 0, stream>>>(x, Wal, Wet, Wth, alpb, etab, thetab);

  dim3 gb3(32, 8, 3);
  for (int b = 0; b < 4; ++b) {
    const float* xb = x + (size_t)b * 4096 * 1024;
    split_x_kernel<<<1024, 256, 0, stream>>>(xb, xbh, xbl, 4096 * 1024 / 4);
    gemm_ps3_kernel<<<gb3, 256, 0, stream>>>(xbh, xbl, wtqh, wtql, wtkh, wtkl, wtvh, wtvl, lin3,
                                             4096, 1024);
    conv3_kernel<<<24576, 256, 0, stream>>>(lin3, cwq, cbq, cwk, cbk, cwv, cbv, cosT, sinT, qh, kh,
                                            vh, b);
  }

  hipMemsetAsync(bar, 0, 32 * 64 * 4, stream);
  hipFuncSetAttribute((const void*)scan_kernel, hipFuncAttributeMaxDynamicSharedMemorySize,
                      SCAN_LDS_BYTES);
  scan_kernel<<<GRIDN, 512, SCAN_LDS_BYTES, stream>>>(qh, kh, vh, thetab, etab, alpb, W1i, W2i,
                                                      gmm, btt, pslots, oslots, zslots, obuf, bar);

  dim3 gg(128, 8);
  gemm_split_kernel<1><<<gg, 256, 0, stream>>>(x, wtgh, wtgl, gate, 16384, 1024);
  post_kernel<<<16384, 256, 0, stream>>>(obuf, gate, gmm, btt, yh, yl);
  gemm_ps_kernel<<<gg, 256, 0, stream>>>(yh, yl, wtoh, wtol, (float*)d_out, 16384, 1024);
}

// Round 14
// 2608.077 us; speedup vs baseline: 4.1279x; 4.1279x over previous
//
#include <hip/hip_runtime.h>

#define GRIDN 256
#define SPAD 132
#define APAD 33
#define EPSF 1e-6f
#define SCAN_LDS_BYTES ((2 * 32 * SPAD + 2 * 64 * SPAD + 64 * APAD) * 4)

typedef __attribute__((ext_vector_type(8))) short bf16x8;
typedef __attribute__((ext_vector_type(4))) float f32x4;
typedef __attribute__((ext_vector_type(2))) float f32x2;

__device__ __forceinline__ ushort f2bf(float f) {
  unsigned u = __float_as_uint(f);
  u += 0x7FFFu + ((u >> 16) & 1u);
  return (ushort)(u >> 16);
}
__device__ __forceinline__ float bf2f(ushort u) {
  return __uint_as_float(((unsigned)u) << 16);
}
__device__ __forceinline__ float sigf(float x) { return 1.f / (1.f + expf(-x)); }

// ---- XCD-local (L2) coherent slot loads: sc0 bypasses L1, hits own-XCD L2 ----
__device__ __forceinline__ void scload8(const float* b, f32x2 (&o)[8]) {
  asm volatile(
      "global_load_dwordx2 %0, %8, off sc0\n\t"
      "global_load_dwordx2 %1, %9, off sc0\n\t"
      "global_load_dwordx2 %2, %10, off sc0\n\t"
      "global_load_dwordx2 %3, %11, off sc0\n\t"
      "global_load_dwordx2 %4, %12, off sc0\n\t"
      "global_load_dwordx2 %5, %13, off sc0\n\t"
      "global_load_dwordx2 %6, %14, off sc0\n\t"
      "global_load_dwordx2 %7, %15, off sc0\n\t"
      "s_waitcnt vmcnt(0)"
      : "=&v"(o[0]), "=&v"(o[1]), "=&v"(o[2]), "=&v"(o[3]),
        "=&v"(o[4]), "=&v"(o[5]), "=&v"(o[6]), "=&v"(o[7])
      : "v"(b), "v"(b + 8192), "v"(b + 16384), "v"(b + 24576),
        "v"(b + 32768), "v"(b + 40960), "v"(b + 49152), "v"(b + 57344)
      : "memory");
}
__device__ __forceinline__ void scload4(const float* b, f32x4 (&o)[4]) {
  asm volatile(
      "global_load_dwordx4 %0, %4, off sc0\n\t"
      "global_load_dwordx4 %1, %5, off sc0\n\t"
      "global_load_dwordx4 %2, %6, off sc0\n\t"
      "global_load_dwordx4 %3, %7, off sc0\n\t"
      "s_waitcnt vmcnt(0)"
      : "=&v"(o[0]), "=&v"(o[1]), "=&v"(o[2]), "=&v"(o[3])
      : "v"(b), "v"(b + 4), "v"(b + 8), "v"(b + 12)
      : "memory");
}

// ---------------- weight transpose + hi/lo split (5 weights fused, z-dim) ----------------
__global__ void cvt_wT_split5_kernel(const float* __restrict__ W0, const float* __restrict__ W1_,
                                     const float* __restrict__ W2_, const float* __restrict__ W3_,
                                     const float* __restrict__ W4_, ushort* __restrict__ H0,
                                     ushort* __restrict__ L0, ushort* __restrict__ H1,
                                     ushort* __restrict__ L1, ushort* __restrict__ H2,
                                     ushort* __restrict__ L2, ushort* __restrict__ H3,
                                     ushort* __restrict__ L3, ushort* __restrict__ H4,
                                     ushort* __restrict__ L4) {
  __shared__ float tile[64][65];
  int zz = blockIdx.z;
  const float* W = (zz == 0) ? W0 : (zz == 1) ? W1_ : (zz == 2) ? W2_ : (zz == 3) ? W3_ : W4_;
  ushort* WTh = (zz == 0) ? H0 : (zz == 1) ? H1 : (zz == 2) ? H2 : (zz == 3) ? H3 : H4;
  ushort* WTl = (zz == 0) ? L0 : (zz == 1) ? L1 : (zz == 2) ? L2 : (zz == 3) ? L3 : L4;
  int bk = blockIdx.x * 64, bn = blockIdx.y * 64;
  int tid = threadIdx.x;
  int r = tid >> 2, c0 = (tid & 3) * 16;
#pragma unroll
  for (int q = 0; q < 16; q += 4) {
    float4 v = *(const float4*)&W[(size_t)(bk + r) * 1024 + bn + c0 + q];
    tile[r][c0 + q] = v.x; tile[r][c0 + q + 1] = v.y;
    tile[r][c0 + q + 2] = v.z; tile[r][c0 + q + 3] = v.w;
  }
  __syncthreads();
  uint ph[8], pl[8];
#pragma unroll
  for (int q = 0; q < 8; ++q) {
    float v0 = tile[c0 + 2 * q][r], v1 = tile[c0 + 2 * q + 1][r];
    ushort h0 = f2bf(v0), h1 = f2bf(v1);
    ushort l0 = f2bf(v0 - bf2f(h0)), l1 = f2bf(v1 - bf2f(h1));
    ph[q] = (uint)h0 | ((uint)h1 << 16);
    pl[q] = (uint)l0 | ((uint)l1 << 16);
  }
  *(uint4*)&WTh[(size_t)(bn + r) * 1024 + bk + c0] = make_uint4(ph[0], ph[1], ph[2], ph[3]);
  *(uint4*)&WTh[(size_t)(bn + r) * 1024 + bk + c0 + 8] = make_uint4(ph[4], ph[5], ph[6], ph[7]);
  *(uint4*)&WTl[(size_t)(bn + r) * 1024 + bk + c0] = make_uint4(pl[0], pl[1], pl[2], pl[3]);
  *(uint4*)&WTl[(size_t)(bn + r) * 1024 + bk + c0 + 8] = make_uint4(pl[4], pl[5], pl[6], pl[7]);
}

// ---------------- fp32 -> bf16 hi/lo split (A-side) ----------------
__global__ void split_x_kernel(const float* __restrict__ src, ushort* __restrict__ dh,
                               ushort* __restrict__ dl, int n4) {
  int i = blockIdx.x * blockDim.x + threadIdx.x;
  int stride = gridDim.x * blockDim.x;
  for (; i < n4; i += stride) {
    float4 v = ((const float4*)src)[i];
    float a[4] = {v.x, v.y, v.z, v.w};
    ushort hh[4], ll[4];
#pragma unroll
    for (int q = 0; q < 4; ++q) {
      hh[q] = f2bf(a[q]);
      ll[q] = f2bf(a[q] - bf2f(hh[q]));
    }
    ((ushort4*)dh)[i] = make_ushort4(hh[0], hh[1], hh[2], hh[3]);
    ((ushort4*)dl)[i] = make_ushort4(ll[0], ll[1], ll[2], ll[3]);
  }
}

// ---------------- rope table ----------------
__global__ void rope_table_kernel(float* __restrict__ cosT, float* __restrict__ sinT) {
  int t = blockIdx.x, i = threadIdx.x; // i in [0,64)
  float inv = expf(-(float)i * (9.210340371976184f / 64.f)); // 10000^(-i/64)
  float f = (float)t * inv;
  cosT[t * 64 + i] = cosf(f);
  sinT[t * 64 + i] = sinf(f);
}

// ---------------- theta/eta/alpha small projections (fp32) ----------------
__global__ void proj_small_kernel(const float* __restrict__ x, const float* __restrict__ Wa,
                                  const float* __restrict__ We, const float* __restrict__ Wt,
                                  float* __restrict__ alp, float* __restrict__ eta,
                                  float* __restrict__ theta) {
  __shared__ float wl[24][SPAD];
  int row = blockIdx.x * 256 + threadIdx.x;
  float acc[24];
#pragma unroll
  for (int c = 0; c < 24; ++c) acc[c] = 0.f;
  for (int kc = 0; kc < 1024; kc += 128) {
    __syncthreads();
    for (int e = threadIdx.x; e < 24 * 128; e += 256) {
      int c = e >> 7, k = e & 127;
      const float* src = (c < 8) ? Wa : (c < 16) ? We : Wt;
      wl[c][k] = src[(size_t)(kc + k) * 8 + (c & 7)];
    }
    __syncthreads();
    for (int k = 0; k < 128; k += 4) {
      float4 xv = *(const float4*)&x[(size_t)row * 1024 + kc + k];
#pragma unroll
      for (int c = 0; c < 24; ++c) {
        float4 wv = *(const float4*)&wl[c][k];
        acc[c] += xv.x * wv.x + xv.y * wv.y + xv.z * wv.z + xv.w * wv.w;
      }
    }
  }
#pragma unroll
  for (int c = 0; c < 8; ++c) alp[(size_t)row * 8 + c] = sigf(acc[c]);
#pragma unroll
  for (int c = 0; c < 8; ++c) eta[(size_t)row * 8 + c] = sigf(acc[8 + c]);
#pragma unroll
  for (int c = 0; c < 8; ++c) theta[(size_t)row * 8 + c] = sigf(acc[16 + c]);
}

// ---------------- split-bf16 MFMA GEMM, A fp32 in-kernel split (gate only) ----------------
template <int EPI>
__global__ __launch_bounds__(256) void gemm_split_kernel(const float* __restrict__ A,
                                                         const ushort* __restrict__ BTh,
                                                         const ushort* __restrict__ BTl,
                                                         float* __restrict__ C, int M, int N) {
  __shared__ ushort sAh[128][40];
  __shared__ ushort sAl[128][40];
  __shared__ ushort sBh[128][40];
  __shared__ ushort sBl[128][40];
  const int K = 1024;
  int m0 = blockIdx.x * 128, n0 = blockIdx.y * 128;
  int tid = threadIdx.x;
  int w = tid >> 6, lane = tid & 63;
  int wr = (w >> 1) * 64, wc = (w & 1) * 64;
  f32x4 acc[4][4];
#pragma unroll
  for (int i = 0; i < 4; ++i)
#pragma unroll
    for (int jq = 0; jq < 4; ++jq) acc[i][jq] = (f32x4){0.f, 0.f, 0.f, 0.f};
  int lr = tid >> 1, ls = (tid & 1) * 16;
  const float* ga = A + (size_t)(m0 + lr) * K + ls;
  const ushort* gbh = BTh + (size_t)(n0 + lr) * K + ls;
  const ushort* gbl = BTl + (size_t)(n0 + lr) * K + ls;
  for (int k0 = 0; k0 < K; k0 += 32) {
    float av[16];
    *(float4*)&av[0] = *(const float4*)(ga + k0);
    *(float4*)&av[4] = *(const float4*)(ga + k0 + 4);
    *(float4*)&av[8] = *(const float4*)(ga + k0 + 8);
    *(float4*)&av[12] = *(const float4*)(ga + k0 + 12);
    uint4 bh0 = *(const uint4*)(gbh + k0);
    uint4 bh1 = *(const uint4*)(gbh + k0 + 8);
    uint4 bl0 = *(const uint4*)(gbl + k0);
    uint4 bl1 = *(const uint4*)(gbl + k0 + 8);
    uint ph[8], pl[8];
#pragma unroll
    for (int q = 0; q < 8; ++q) {
      float v0 = av[2 * q], v1 = av[2 * q + 1];
      ushort h0 = f2bf(v0), h1 = f2bf(v1);
      ushort l0 = f2bf(v0 - bf2f(h0)), l1 = f2bf(v1 - bf2f(h1));
      ph[q] = (uint)h0 | ((uint)h1 << 16);
      pl[q] = (uint)l0 | ((uint)l1 << 16);
    }
    __syncthreads();
    *(uint4*)&sAh[lr][ls] = make_uint4(ph[0], ph[1], ph[2], ph[3]);
    *(uint4*)&sAh[lr][ls + 8] = make_uint4(ph[4], ph[5], ph[6], ph[7]);
    *(uint4*)&sAl[lr][ls] = make_uint4(pl[0], pl[1], pl[2], pl[3]);
    *(uint4*)&sAl[lr][ls + 8] = make_uint4(pl[4], pl[5], pl[6], pl[7]);
    *(uint4*)&sBh[lr][ls] = bh0; *(uint4*)&sBh[lr][ls + 8] = bh1;
    *(uint4*)&sBl[lr][ls] = bl0; *(uint4*)&sBl[lr][ls + 8] = bl1;
    __syncthreads();
    int ra = wr + (lane & 15), rb = wc + (lane & 15), kk = (lane >> 4) * 8;
    bf16x8 ah[4], al[4], bh[4], bl[4];
#pragma unroll
    for (int q = 0; q < 4; ++q) {
      ah[q] = *(const bf16x8*)&sAh[ra + q * 16][kk];
      al[q] = *(const bf16x8*)&sAl[ra + q * 16][kk];
      bh[q] = *(const bf16x8*)&sBh[rb + q * 16][kk];
      bl[q] = *(const bf16x8*)&sBl[rb + q * 16][kk];
    }
#pragma unroll
    for (int mt = 0; mt < 4; ++mt)
#pragma unroll
      for (int nt = 0; nt < 4; ++nt) {
        acc[mt][nt] = __builtin_amdgcn_mfma_f32_16x16x32_bf16(ah[mt], bh[nt], acc[mt][nt], 0, 0, 0);
        acc[mt][nt] = __builtin_amdgcn_mfma_f32_16x16x32_bf16(ah[mt], bl[nt], acc[mt][nt], 0, 0, 0);
        acc[mt][nt] = __builtin_amdgcn_mfma_f32_16x16x32_bf16(al[mt], bh[nt], acc[mt][nt], 0, 0, 0);
      }
  }
  int colb = n0 + wc + (lane & 15);
#pragma unroll
  for (int mt = 0; mt < 4; ++mt) {
#pragma unroll
    for (int nt = 0; nt < 4; ++nt) {
#pragma unroll
      for (int jq = 0; jq < 4; ++jq) {
        int row = m0 + wr + mt * 16 + (lane >> 4) * 4 + jq;
        int cc = colb + nt * 16;
        float v = acc[mt][nt][jq];
        if (EPI == 0) C[(size_t)row * N + cc] = v;
        else C[(size_t)row * N + cc] = v * sigf(v);
      }
    }
  }
}

// ---------------- split-bf16 MFMA GEMM, A pre-split (final o) ----------------
__global__ __launch_bounds__(256) void gemm_ps_kernel(const ushort* __restrict__ Ah,
                                                      const ushort* __restrict__ Al,
                                                      const ushort* __restrict__ BTh,
                                                      const ushort* __restrict__ BTl,
                                                      float* __restrict__ C, int M, int N) {
  __shared__ ushort sAh[128][40];
  __shared__ ushort sAl[128][40];
  __shared__ ushort sBh[128][40];
  __shared__ ushort sBl[128][40];
  const int K = 1024;
  int m0 = blockIdx.x * 128, n0 = blockIdx.y * 128;
  int tid = threadIdx.x;
  int w = tid >> 6, lane = tid & 63;
  int wr = (w >> 1) * 64, wc = (w & 1) * 64;
  f32x4 acc[4][4];
#pragma unroll
  for (int i = 0; i < 4; ++i)
#pragma unroll
    for (int jq = 0; jq < 4; ++jq) acc[i][jq] = (f32x4){0.f, 0.f, 0.f, 0.f};
  int lr = tid >> 1, ls = (tid & 1) * 16;
  const ushort* gah = Ah + (size_t)(m0 + lr) * K + ls;
  const ushort* gal = Al + (size_t)(m0 + lr) * K + ls;
  const ushort* gbh = BTh + (size_t)(n0 + lr) * K + ls;
  const ushort* gbl = BTl + (size_t)(n0 + lr) * K + ls;
  for (int k0 = 0; k0 < K; k0 += 32) {
    uint4 ah0 = *(const uint4*)(gah + k0);
    uint4 ah1 = *(const uint4*)(gah + k0 + 8);
    uint4 al0 = *(const uint4*)(gal + k0);
    uint4 al1 = *(const uint4*)(gal + k0 + 8);
    uint4 bh0 = *(const uint4*)(gbh + k0);
    uint4 bh1 = *(const uint4*)(gbh + k0 + 8);
    uint4 bl0 = *(const uint4*)(gbl + k0);
    uint4 bl1 = *(const uint4*)(gbl + k0 + 8);
    __syncthreads();
    *(uint4*)&sAh[lr][ls] = ah0; *(uint4*)&sAh[lr][ls + 8] = ah1;
    *(uint4*)&sAl[lr][ls] = al0; *(uint4*)&sAl[lr][ls + 8] = al1;
    *(uint4*)&sBh[lr][ls] = bh0; *(uint4*)&sBh[lr][ls + 8] = bh1;
    *(uint4*)&sBl[lr][ls] = bl0; *(uint4*)&sBl[lr][ls + 8] = bl1;
    __syncthreads();
    int ra = wr + (lane & 15), rb = wc + (lane & 15), kk = (lane >> 4) * 8;
    bf16x8 ah[4], al[4], bh[4], bl[4];
#pragma unroll
    for (int q = 0; q < 4; ++q) {
      ah[q] = *(const bf16x8*)&sAh[ra + q * 16][kk];
      al[q] = *(const bf16x8*)&sAl[ra + q * 16][kk];
      bh[q] = *(const bf16x8*)&sBh[rb + q * 16][kk];
      bl[q] = *(const bf16x8*)&sBl[rb + q * 16][kk];
    }
#pragma unroll
    for (int mt = 0; mt < 4; ++mt)
#pragma unroll
      for (int nt = 0; nt < 4; ++nt) {
        acc[mt][nt] = __builtin_amdgcn_mfma_f32_16x16x32_bf16(ah[mt], bh[nt], acc[mt][nt], 0, 0, 0);
        acc[mt][nt] = __builtin_amdgcn_mfma_f32_16x16x32_bf16(ah[mt], bl[nt], acc[mt][nt], 0, 0, 0);
        acc[mt][nt] = __builtin_amdgcn_mfma_f32_16x16x32_bf16(al[mt], bh[nt], acc[mt][nt], 0, 0, 0);
      }
  }
  int colb = n0 + wc + (lane & 15);
#pragma unroll
  for (int mt = 0; mt < 4; ++mt) {
#pragma unroll
    for (int nt = 0; nt < 4; ++nt) {
#pragma unroll
      for (int jq = 0; jq < 4; ++jq) {
        int row = m0 + wr + mt * 16 + (lane >> 4) * 4 + jq;
        int cc = colb + nt * 16;
        C[(size_t)row * N + cc] = acc[mt][nt][jq];
      }
    }
  }
}

// ---------------- fused q/k/v projection GEMMs (blockIdx.z selects weight) ----------------
__global__ __launch_bounds__(256) void gemm_ps3_kernel(const ushort* __restrict__ Ah,
                                                       const ushort* __restrict__ Al,
                                                       const ushort* __restrict__ B0h,
                                                       const ushort* __restrict__ B0l,
                                                       const ushort* __restrict__ B1h,
                                                       const ushort* __restrict__ B1l,
                                                       const ushort* __restrict__ B2h,
                                                       const ushort* __restrict__ B2l,
                                                       float* __restrict__ C, int M, int N) {
  __shared__ ushort sAh[128][40];
  __shared__ ushort sAl[128][40];
  __shared__ ushort sBh[128][40];
  __shared__ ushort sBl[128][40];
  const int K = 1024;
  int zz = blockIdx.z;
  const ushort* BTh = (zz == 0) ? B0h : (zz == 1) ? B1h : B2h;
  const ushort* BTl = (zz == 0) ? B0l : (zz == 1) ? B1l : B2l;
  float* Cz = C + (size_t)zz * M * N;
  int m0 = blockIdx.x * 128, n0 = blockIdx.y * 128;
  int tid = threadIdx.x;
  int w = tid >> 6, lane = tid & 63;
  int wr = (w >> 1) * 64, wc = (w & 1) * 64;
  f32x4 acc[4][4];
#pragma unroll
  for (int i = 0; i < 4; ++i)
#pragma unroll
    for (int jq = 0; jq < 4; ++jq) acc[i][jq] = (f32x4){0.f, 0.f, 0.f, 0.f};
  int lr = tid >> 1, ls = (tid & 1) * 16;
  const ushort* gah = Ah + (size_t)(m0 + lr) * K + ls;
  const ushort* gal = Al + (size_t)(m0 + lr) * K + ls;
  const ushort* gbh = BTh + (size_t)(n0 + lr) * K + ls;
  const ushort* gbl = BTl + (size_t)(n0 + lr) * K + ls;
  for (int k0 = 0; k0 < K; k0 += 32) {
    uint4 ah0 = *(const uint4*)(gah + k0);
    uint4 ah1 = *(const uint4*)(gah + k0 + 8);
    uint4 al0 = *(const uint4*)(gal + k0);
    uint4 al1 = *(const uint4*)(gal + k0 + 8);
    uint4 bh0 = *(const uint4*)(gbh + k0);
    uint4 bh1 = *(const uint4*)(gbh + k0 + 8);
    uint4 bl0 = *(const uint4*)(gbl + k0);
    uint4 bl1 = *(const uint4*)(gbl + k0 + 8);
    __syncthreads();
    *(uint4*)&sAh[lr][ls] = ah0; *(uint4*)&sAh[lr][ls + 8] = ah1;
    *(uint4*)&sAl[lr][ls] = al0; *(uint4*)&sAl[lr][ls + 8] = al1;
    *(uint4*)&sBh[lr][ls] = bh0; *(uint4*)&sBh[lr][ls + 8] = bh1;
    *(uint4*)&sBl[lr][ls] = bl0; *(uint4*)&sBl[lr][ls + 8] = bl1;
    __syncthreads();
    int ra = wr + (lane & 15), rb = wc + (lane & 15), kk = (lane >> 4) * 8;
    bf16x8 ah[4], al[4], bh[4], bl[4];
#pragma unroll
    for (int q = 0; q < 4; ++q) {
      ah[q] = *(const bf16x8*)&sAh[ra + q * 16][kk];
      al[q] = *(const bf16x8*)&sAl[ra + q * 16][kk];
      bh[q] = *(const bf16x8*)&sBh[rb + q * 16][kk];
      bl[q] = *(const bf16x8*)&sBl[rb + q * 16][kk];
    }
#pragma unroll
    for (int mt = 0; mt < 4; ++mt)
#pragma unroll
      for (int nt = 0; nt < 4; ++nt) {
        acc[mt][nt] = __builtin_amdgcn_mfma_f32_16x16x32_bf16(ah[mt], bh[nt], acc[mt][nt], 0, 0, 0);
        acc[mt][nt] = __builtin_amdgcn_mfma_f32_16x16x32_bf16(ah[mt], bl[nt], acc[mt][nt], 0, 0, 0);
        acc[mt][nt] = __builtin_amdgcn_mfma_f32_16x16x32_bf16(al[mt], bh[nt], acc[mt][nt], 0, 0, 0);
      }
  }
  int colb = n0 + wc + (lane & 15);
#pragma unroll
  for (int mt = 0; mt < 4; ++mt) {
#pragma unroll
    for (int nt = 0; nt < 4; ++nt) {
#pragma unroll
      for (int jq = 0; jq < 4; ++jq) {
        int row = m0 + wr + mt * 16 + (lane >> 4) * 4 + jq;
        int cc = colb + nt * 16;
        Cz[(size_t)row * N + cc] = acc[mt][nt][jq];
      }
    }
  }
}

// ---------------- merged depthwise conv(4)+silu(+l2norm+rope) for q,k,v of one b ----------------
__global__ void conv3_kernel(const float* __restrict__ lin3, const float* __restrict__ cwq,
                             const float* __restrict__ cbq, const float* __restrict__ cwk,
                             const float* __restrict__ cbk, const float* __restrict__ cwv,
                             const float* __restrict__ cbv, const float* __restrict__ cosT,
                             const float* __restrict__ sinT, float* __restrict__ qh,
                             float* __restrict__ kh, float* __restrict__ vh, int b) {
  int u = blockIdx.x * 4 + (threadIdx.x >> 6);  // [0, 3*32768)
  int which = u >> 15;
  int uu = u & 32767;
  int lane = threadIdx.x & 63;
  int h = uu >> 12, t = uu & 4095;
  int c0 = h * 128 + lane;
  const float* lin = lin3 + (size_t)which * 4096 * 1024;
  const float* cw = (which == 0) ? cwq : (which == 1) ? cwk : cwv;
  const float* cb = (which == 0) ? cbq : (which == 1) ? cbk : cbv;
  float* outp = (which == 0) ? qh : (which == 1) ? kh : vh;
  float4 w0 = *(const float4*)&cw[(size_t)c0 * 4];
  float4 w1 = *(const float4*)&cw[(size_t)(c0 + 64) * 4];
  float w0a[4] = {w0.x, w0.y, w0.z, w0.w};
  float w1a[4] = {w1.x, w1.y, w1.z, w1.w};
  float y0 = cb[c0], y1 = cb[c0 + 64];
  const float* base = lin + c0;
#pragma unroll
  for (int j = 0; j < 4; ++j) {
    int tj = t - 3 + j;
    if (tj >= 0) {
      y0 += w0a[j] * base[(size_t)tj * 1024];
      y1 += w1a[j] * base[(size_t)tj * 1024 + 64];
    }
  }
  y0 = y0 * sigf(y0);
  y1 = y1 * sigf(y1);
  if (which < 2) {
    float ss = y0 * y0 + y1 * y1;
#pragma unroll
    for (int off = 1; off < 64; off <<= 1) ss += __shfl_xor(ss, off);
    float sc = 1.f / fmaxf(sqrtf(ss), 1e-12f);
    y0 *= sc; y1 *= sc;
    float cv = cosT[t * 64 + lane], sv = sinT[t * 64 + lane];
    float o0 = y0 * cv - y1 * sv;
    float o1 = y1 * cv + y0 * sv;
    y0 = o0; y1 = o1;
  }
  int p = b * 8 + h;
  float* dst = outp + (((size_t)p * 64 + (t >> 6)) * 64 + (t & 63)) * 128;
  dst[lane] = y0;
  dst[lane + 64] = y1;
}

// ---------------- pair-local sync ----------------
__device__ __forceinline__ void pair_sync(unsigned* ctr, unsigned target) {
  asm volatile("s_waitcnt vmcnt(0)" ::: "memory");
  __syncthreads();
  if (threadIdx.x == 0) {
    __hip_atomic_fetch_add(ctr, 1u, __ATOMIC_RELAXED, __HIP_MEMORY_SCOPE_AGENT);
    int spins = 0;
    while (__hip_atomic_load(ctr, __ATOMIC_RELAXED, __HIP_MEMORY_SCOPE_AGENT) < target) {
      __builtin_amdgcn_s_sleep(4);
      if (++spins > (1 << 18)) break;
    }
  }
  __syncthreads();
}
__device__ __forceinline__ double wredd(double v) {
#pragma unroll
  for (int off = 1; off < 64; off <<= 1) v += __shfl_xor(v, off);
  return v;
}

// ---------------- the chunked TTT scan (round-12/round-10 structure, SPAD=132) ----------------
__global__ __launch_bounds__(512, 2) void scan_kernel(
    const float* qh, const float* __restrict__ kh, const float* __restrict__ vh,
    const float* __restrict__ theta, const float* __restrict__ etab, const float* __restrict__ alpb,
    const float* __restrict__ W1i, const float* __restrict__ W2i,
    const float* __restrict__ gmm, const float* __restrict__ btt,
    float* __restrict__ pslots, float* __restrict__ oslots, float* __restrict__ zslots,
    float* obuf, unsigned* __restrict__ bar) {
  extern __shared__ float lds[];
  float* sW1 = lds;                  // [32][SPAD]
  float* sW2 = sW1 + 32 * SPAD;      // [32][SPAD]
  float* sK = sW2 + 32 * SPAD;       // [64][SPAD]
  float* sZ = sK + 64 * SPAD;        // [64][SPAD]
  float* sA = sZ + 64 * SPAD;        // [64][APAD]

  int wg = blockIdx.x;
  int xcd = wg & 7, jj0 = wg >> 3;
  int p = xcd * 4 + (jj0 >> 3), mb = jj0 & 7;
  int b = p >> 3, hh = p & 7;
  int m0 = mb * 32;
  int tid = threadIdx.x;
  unsigned* ctr = bar + (size_t)p * 64;

  for (int it = 0; it < 8; ++it) {
    int e = tid + it * 512;
    int m = e & 31, d = e >> 5;
    sW1[m * SPAD + d] = W1i[((size_t)hh * 128 + d) * 256 + m0 + m];
    sW2[m * SPAD + d] = W2i[((size_t)hh * 256 + m0 + m) * 128 + d];
  }
  float rS1[8], rS2[8];
#pragma unroll
  for (int e = 0; e < 8; ++e) { rS1[e] = 0.f; rS2[e] = 0.f; }

  const float* khp = kh + (size_t)p * (64 * 64 * 128);
  const float* qhp = qh + (size_t)p * (64 * 64 * 128);
  const float* vhp = vh + (size_t)p * (64 * 64 * 128);

  int tm = tid & 31, ti = tid >> 5;
  int i0 = ti * 4;
  int d0p = tm * 4;
  int dg = ti * 8;

  int wid = tid >> 6, lane = tid & 63;
  int rw = mb * 8 + wid;
  int dl = lane * 2;
  float g0 = gmm[hh * 128 + dl], g1 = gmm[hh * 128 + dl + 1];
  float b0 = btt[hh * 128 + dl], b1 = btt[hh * 128 + dl + 1];

  float hreg[4];
  __syncthreads();

  for (int c = 0; c < 64; ++c) {
    // ---- P1: load K+Q tiles to regs (nt), stage K to LDS, hold Q ----
    f32x4 qreg[4];
    {
      const float* srcK = khp + (size_t)c * 8192;
      const float* srcQ = qhp + (size_t)c * 8192;
      f32x4 kreg[4];
#pragma unroll
      for (int it = 0; it < 4; ++it) {
        int e = tid * 4 + it * 2048;
        kreg[it] = __builtin_nontemporal_load((const f32x4*)&srcK[e]);
        qreg[it] = __builtin_nontemporal_load((const f32x4*)&srcQ[e]);
      }
#pragma unroll
      for (int it = 0; it < 4; ++it) {
        int e = tid * 4 + it * 2048;
        *(f32x4*)&sK[(e >> 7) * SPAD + (e & 127)] = kreg[it];
      }
    }
    __syncthreads();
    // h = k@W1block ; a = silu(h)
    {
      float acc[4] = {0.f, 0.f, 0.f, 0.f};
      for (int d = 0; d < 128; d += 16) {
        float4 wv[4], kv4[4][4];
#pragma unroll
        for (int q = 0; q < 4; ++q) wv[q] = *(const float4*)&sW1[tm * SPAD + d + 4 * q];
#pragma unroll
        for (int r = 0; r < 4; ++r)
#pragma unroll
          for (int q = 0; q < 4; ++q) kv4[r][q] = *(const float4*)&sK[(i0 + r) * SPAD + d + 4 * q];
#pragma unroll
        for (int q = 0; q < 4; ++q)
#pragma unroll
          for (int r = 0; r < 4; ++r)
            acc[r] += kv4[r][q].x * wv[q].x + kv4[r][q].y * wv[q].y +
                      kv4[r][q].z * wv[q].z + kv4[r][q].w * wv[q].w;
      }
#pragma unroll
      for (int r = 0; r < 4; ++r) {
        hreg[r] = acc[r];
        sA[(i0 + r) * APAD + tm] = acc[r] * sigf(acc[r]);
      }
    }
    __syncthreads();
    // pred partial = a(:,block) @ W2block -> slot (plain stores -> own-XCD L2)
    {
      float pacc[4][4] = {{0.f}};
      for (int m = 0; m < 32; m += 8) {
        float4 wv[8];
        float av[4][8];
#pragma unroll
        for (int mm = 0; mm < 8; ++mm) wv[mm] = *(const float4*)&sW2[(m + mm) * SPAD + d0p];
#pragma unroll
        for (int r = 0; r < 4; ++r)
#pragma unroll
          for (int mm = 0; mm < 8; ++mm) av[r][mm] = sA[(i0 + r) * APAD + m + mm];
#pragma unroll
        for (int mm = 0; mm < 8; ++mm)
#pragma unroll
          for (int r = 0; r < 4; ++r) {
            pacc[r][0] += av[r][mm] * wv[mm].x; pacc[r][1] += av[r][mm] * wv[mm].y;
            pacc[r][2] += av[r][mm] * wv[mm].z; pacc[r][3] += av[r][mm] * wv[mm].w;
          }
      }
      float* ps = pslots + (((size_t)(c & 1) * 32 + p) * 8 + mb) * 8192;
#pragma unroll
      for (int r = 0; r < 4; ++r)
        *(float4*)&ps[(i0 + r) * 128 + d0p] =
            make_float4(pacc[r][0], pacc[r][1], pacc[r][2], pacc[r][3]);
    }
    pair_sync(ctr, 16u * c + 8u);
    // ---- P2: distributed pred-reduce + fp64 LN-l2-bwd for own 8 rows; z -> slot ----
    {
      f32x2 ot[8];
      if (c > 0) {
        const float* ob =
            oslots + ((size_t)((c - 1) & 1) * 32 + p) * 8 * 8192 + rw * 128 + dl;
        scload8(ob, ot);
      }
      const float* pb = pslots + ((size_t)(c & 1) * 32 + p) * 8 * 8192 + rw * 128 + dl;
      f32x2 pt[8];
      scload8(pb, pt);
      f32x2 vld = __builtin_nontemporal_load((const f32x2*)&vhp[(size_t)c * 8192 + rw * 128 + dl]);
      float pr0 = 0.f, pr1 = 0.f;
#pragma unroll
      for (int m2 = 0; m2 < 8; ++m2) { pr0 += pt[m2][0]; pr1 += pt[m2][1]; }
      double s = (double)pr0 + (double)pr1;
      s = wredd(s);
      double mu = s * (1.0 / 128.0);
      double dd0 = (double)pr0 - mu, dd1 = (double)pr1 - mu;
      double vp = wredd(dd0 * dd0 + dd1 * dd1);
      double rstd = 1.0 / sqrt(vp * (1.0 / 128.0) + (double)EPSF);
      double xh0 = dd0 * rstd, xh1 = dd1 * rstd;
      double gxh0 = 2.0 * (((double)g0 * xh0 + (double)b0) - (double)vld[0]) * (double)g0;
      double gxh1 = 2.0 * (((double)g1 * xh1 + (double)b1) - (double)vld[1]) * (double)g1;
      double s1 = wredd(gxh0 + gxh1);
      double s2 = wredd(gxh0 * xh0 + gxh1 * xh1);
      float th = theta[((size_t)b * 4096 + c * 64 + rw) * 8 + hh];
      double zsc = rstd * (1.0 / 128.0) * (double)th;
      float z0 = (float)((128.0 * gxh0 - s1 - xh0 * s2) * zsc);
      float z1 = (float)((128.0 * gxh1 - s1 - xh1 * s2) * zsc);
      float* zs = zslots + ((size_t)(c & 1) * 32 + p) * 8192;
      *(f32x2*)&zs[rw * 128 + dl] = (f32x2){z0, z1};
      if (c > 0) {
        float o0 = 0.f, o1 = 0.f;
#pragma unroll
        for (int m2 = 0; m2 < 8; ++m2) { o0 += ot[m2][0]; o1 += ot[m2][1]; }
        __builtin_nontemporal_store(
            (f32x2){o0, o1},
            (f32x2*)&obuf[(((size_t)p * 64 + (c - 1)) * 64 + rw) * 128 + dl]);
      }
    }
    pair_sync(ctr, 16u * c + 16u);
    // ---- P3: read full z -> sZ (sc0 loads) ----
    {
      int zr = tid >> 3, zc = (tid & 7) * 16;
      const float* zb = zslots + ((size_t)(c & 1) * 32 + p) * 8192 + zr * 128 + zc;
      f32x4 zt[4];
      scload4(zb, zt);
#pragma unroll
      for (int j = 0; j < 4; ++j) *(f32x4*)&sZ[zr * SPAD + zc + 4 * j] = zt[j];
    }
    __syncthreads();
    // gW2 = a^T z  (own m rows)
    float gw2[8];
    {
#pragma unroll
      for (int e = 0; e < 8; ++e) gw2[e] = 0.f;
      for (int i = 0; i < 64; i += 8) {
        float av[8];
        float4 z0[8], z1[8];
#pragma unroll
        for (int ii = 0; ii < 8; ++ii) av[ii] = sA[(i + ii) * APAD + tm];
#pragma unroll
        for (int ii = 0; ii < 8; ++ii) {
          z0[ii] = *(const float4*)&sZ[(i + ii) * SPAD + dg];
          z1[ii] = *(const float4*)&sZ[(i + ii) * SPAD + dg + 4];
        }
#pragma unroll
        for (int ii = 0; ii < 8; ++ii) {
          gw2[0] += av[ii] * z0[ii].x; gw2[1] += av[ii] * z0[ii].y;
          gw2[2] += av[ii] * z0[ii].z; gw2[3] += av[ii] * z0[ii].w;
          gw2[4] += av[ii] * z1[ii].x; gw2[5] += av[ii] * z1[ii].y;
          gw2[6] += av[ii] * z1[ii].z; gw2[7] += av[ii] * z1[ii].w;
        }
      }
    }
    // gh = (z @ W2block^T) * silu'(h)
    float ghr[4];
    {
      float acc[4] = {0.f, 0.f, 0.f, 0.f};
      for (int d = 0; d < 128; d += 16) {
        float4 wv[4], zv4[4][4];
#pragma unroll
        for (int q = 0; q < 4; ++q) wv[q] = *(const float4*)&sW2[tm * SPAD + d + 4 * q];
#pragma unroll
        for (int r = 0; r < 4; ++r)
#pragma unroll
          for (int q = 0; q < 4; ++q) zv4[r][q] = *(const float4*)&sZ[(i0 + r) * SPAD + d + 4 * q];
#pragma unroll
        for (int q = 0; q < 4; ++q)
#pragma unroll
          for (int r = 0; r < 4; ++r)
            acc[r] += zv4[r][q].x * wv[q].x + zv4[r][q].y * wv[q].y +
                      zv4[r][q].z * wv[q].z + zv4[r][q].w * wv[q].w;
      }
#pragma unroll
      for (int r = 0; r < 4; ++r) {
        float hv = hreg[r];
        float sg = sigf(hv);
        ghr[r] = acc[r] * (sg + hv * sg * (1.f - sg));
      }
    }
    __syncthreads();
#pragma unroll
    for (int r = 0; r < 4; ++r) sA[(i0 + r) * APAD + tm] = ghr[r];
    __syncthreads();
    // gW1 = k^T gh  (own m cols) ; state update (S in regs)
    {
      float gw1[8];
#pragma unroll
      for (int e = 0; e < 8; ++e) gw1[e] = 0.f;
      for (int i = 0; i < 64; i += 8) {
        float gvv[8];
        float4 k0[8], k1[8];
#pragma unroll
        for (int ii = 0; ii < 8; ++ii) gvv[ii] = sA[(i + ii) * APAD + tm];
#pragma unroll
        for (int ii = 0; ii < 8; ++ii) {
          k0[ii] = *(const float4*)&sK[(i + ii) * SPAD + dg];
          k1[ii] = *(const float4*)&sK[(i + ii) * SPAD + dg + 4];
        }
#pragma unroll
        for (int ii = 0; ii < 8; ++ii) {
          gw1[0] += gvv[ii] * k0[ii].x; gw1[1] += gvv[ii] * k0[ii].y;
          gw1[2] += gvv[ii] * k0[ii].z; gw1[3] += gvv[ii] * k0[ii].w;
          gw1[4] += gvv[ii] * k1[ii].x; gw1[5] += gvv[ii] * k1[ii].y;
          gw1[6] += gvv[ii] * k1[ii].z; gw1[7] += gvv[ii] * k1[ii].w;
        }
      }
      float ei = etab[((size_t)b * 4096 + c * 64 + 63) * 8 + hh];
      float ai = alpb[((size_t)b * 4096 + c * 64 + 63) * 8 + hh];
      float om = 1.f - ai;
#pragma unroll
      for (int g2 = 0; g2 < 2; ++g2) {
        int dd = dg + g2 * 4;
#pragma unroll
        for (int j = 0; j < 4; ++j) rS1[g2 * 4 + j] = ei * rS1[g2 * 4 + j] - gw1[g2 * 4 + j];
        float4 w1v = *(const float4*)&sW1[tm * SPAD + dd];
        w1v.x = om * w1v.x + rS1[g2 * 4 + 0]; w1v.y = om * w1v.y + rS1[g2 * 4 + 1];
        w1v.z = om * w1v.z + rS1[g2 * 4 + 2]; w1v.w = om * w1v.w + rS1[g2 * 4 + 3];
        *(float4*)&sW1[tm * SPAD + dd] = w1v;
#pragma unroll
        for (int j = 0; j < 4; ++j) rS2[g2 * 4 + j] = ei * rS2[g2 * 4 + j] - gw2[g2 * 4 + j];
        float4 w2v = *(const float4*)&sW2[tm * SPAD + dd];
        w2v.x = om * w2v.x + rS2[g2 * 4 + 0]; w2v.y = om * w2v.y + rS2[g2 * 4 + 1];
        w2v.z = om * w2v.z + rS2[g2 * 4 + 2]; w2v.w = om * w2v.w + rS2[g2 * 4 + 3];
        *(float4*)&sW2[tm * SPAD + dd] = w2v;
      }
    }
    __syncthreads();
    // stage Q tile into sK (from regs)
    {
#pragma unroll
      for (int it = 0; it < 4; ++it) {
        int e = tid * 4 + it * 2048;
        *(f32x4*)&sK[(e >> 7) * SPAD + (e & 127)] = qreg[it];
      }
    }
    __syncthreads();
    // a_o = silu(q @ W1new)
    {
      float acc[4] = {0.f, 0.f, 0.f, 0.f};
      for (int d = 0; d < 128; d += 16) {
        float4 wv[4], kv4[4][4];
#pragma unroll
        for (int q = 0; q < 4; ++q) wv[q] = *(const float4*)&sW1[tm * SPAD + d + 4 * q];
#pragma unroll
        for (int r = 0; r < 4; ++r)
#pragma unroll
          for (int q = 0; q < 4; ++q) kv4[r][q] = *(const float4*)&sK[(i0 + r) * SPAD + d + 4 * q];
#pragma unroll
        for (int q = 0; q < 4; ++q)
#pragma unroll
          for (int r = 0; r < 4; ++r)
            acc[r] += kv4[r][q].x * wv[q].x + kv4[r][q].y * wv[q].y +
                      kv4[r][q].z * wv[q].z + kv4[r][q].w * wv[q].w;
      }
#pragma unroll
      for (int r = 0; r < 4; ++r) sA[(i0 + r) * APAD + tm] = acc[r] * sigf(acc[r]);
    }
    __syncthreads();
    // o partial = a_o @ W2new -> slot (plain stores)
    {
      float oacc[4][4] = {{0.f}};
      for (int m = 0; m < 32; m += 8) {
        float4 wv[8];
        float av[4][8];
#pragma unroll
        for (int mm = 0; mm < 8; ++mm) wv[mm] = *(const float4*)&sW2[(m + mm) * SPAD + d0p];
#pragma unroll
        for (int r = 0; r < 4; ++r)
#pragma unroll
          for (int mm = 0; mm < 8; ++mm) av[r][mm] = sA[(i0 + r) * APAD + m + mm];
#pragma unroll
        for (int mm = 0; mm < 8; ++mm)
#pragma unroll
          for (int r = 0; r < 4; ++r) {
            oacc[r][0] += av[r][mm] * wv[mm].x; oacc[r][1] += av[r][mm] * wv[mm].y;
            oacc[r][2] += av[r][mm] * wv[mm].z; oacc[r][3] += av[r][mm] * wv[mm].w;
          }
      }
      float* os = oslots + (((size_t)(c & 1) * 32 + p) * 8 + mb) * 8192;
#pragma unroll
      for (int r = 0; r < 4; ++r)
        *(float4*)&os[(i0 + r) * 128 + d0p] =
            make_float4(oacc[r][0], oacc[r][1], oacc[r][2], oacc[r][3]);
    }
  }
  // tail: reduce o of chunk 63
  pair_sync(ctr, 16u * 64 + 8u);
  {
    const float* ob = oslots + ((size_t)(63 & 1) * 32 + p) * 8 * 8192 + rw * 128 + dl;
    f32x2 t[8];
    scload8(ob, t);
    float o0 = 0.f, o1 = 0.f;
#pragma unroll
    for (int m2 = 0; m2 < 8; ++m2) { o0 += t[m2][0]; o1 += t[m2][1]; }
    *(f32x2*)&obuf[(((size_t)p * 64 + 63) * 64 + rw) * 128 + dl] = (f32x2){o0, o1};
  }
}

// ---------------- head LN + l2norm + gate -> bf16 hi/lo y ----------------
__global__ __launch_bounds__(256) void post_kernel(const float* __restrict__ obuf,
                                                   const float* __restrict__ gate,
                                                   const float* __restrict__ gmm,
                                                   const float* __restrict__ btt,
                                                   ushort* __restrict__ yh,
                                                   ushort* __restrict__ yl) {
  __shared__ float red[4];
  int row = blockIdx.x;
  int tid = threadIdx.x;
  int ch = tid * 4;
  int h = tid >> 5;
  int bb = row >> 12, t = row & 4095;
  int p = bb * 8 + h, cc = t >> 6, rr = t & 63;
  int dloc = (tid & 31) * 4;
  float4 o = *(const float4*)&obuf[(((size_t)p * 64 + cc) * 64 + rr) * 128 + dloc];
  float s = o.x + o.y + o.z + o.w;
#pragma unroll
  for (int off = 1; off < 32; off <<= 1) s += __shfl_xor(s, off);
  float mu = s * (1.f / 128.f);
  float dx = o.x - mu, dy = o.y - mu, dz = o.z - mu, dw = o.w - mu;
  float vp = dx * dx + dy * dy + dz * dz + dw * dw;
#pragma unroll
  for (int off = 1; off < 32; off <<= 1) vp += __shfl_xor(vp, off);
  float rstd = 1.f / sqrtf(vp * (1.f / 128.f) + EPSF);
  float4 g4 = *(const float4*)&gmm[h * 128 + dloc];
  float4 b4 = *(const float4*)&btt[h * 128 + dloc];
  float y0 = g4.x * (dx * rstd) + b4.x;
  float y1 = g4.y * (dy * rstd) + b4.y;
  float y2 = g4.z * (dz * rstd) + b4.z;
  float y3 = g4.w * (dw * rstd) + b4.w;
  float ss = y0 * y0 + y1 * y1 + y2 * y2 + y3 * y3;
#pragma unroll
  for (int off = 1; off < 64; off <<= 1) ss += __shfl_xor(ss, off);
  if ((tid & 63) == 0) red[tid >> 6] = ss;
  __syncthreads();
  float tot = red[0] + red[1] + red[2] + red[3];
  float sc = 1.f / fmaxf(sqrtf(tot), 1e-12f);
  float4 gt = *(const float4*)&gate[(size_t)row * 1024 + ch];
  float yv[4] = {y0 * sc * gt.x, y1 * sc * gt.y, y2 * sc * gt.z, y3 * sc * gt.w};
  ushort hh[4], ll[4];
#pragma unroll
  for (int q = 0; q < 4; ++q) {
    hh[q] = f2bf(yv[q]);
    ll[q] = f2bf(yv[q] - bf2f(hh[q]));
  }
  *(ushort4*)&yh[(size_t)row * 1024 + ch] = make_ushort4(hh[0], hh[1], hh[2], hh[3]);
  *(ushort4*)&yl[(size_t)row * 1024 + ch] = make_ushort4(ll[0], ll[1], ll[2], ll[3]);
}

// ---------------- host ----------------
extern "C" void kernel_launch(void* const* d_in, const int* in_sizes, int n_in, void* d_out,
                              int out_size, void* d_ws, size_t ws_size, hipStream_t stream) {
  const float* x = (const float*)d_in[0];
  const float* Wq = (const float*)d_in[1];
  const float* Wk = (const float*)d_in[2];
  const float* Wv = (const float*)d_in[3];
  const float* cwq = (const float*)d_in[4];
  const float* cbq = (const float*)d_in[5];
  const float* cwk = (const float*)d_in[6];
  const float* cbk = (const float*)d_in[7];
  const float* cwv = (const float*)d_in[8];
  const float* cbv = (const float*)d_in[9];
  const float* Wal = (const float*)d_in[10];
  const float* Wet = (const float*)d_in[11];
  const float* Wth = (const float*)d_in[12];
  const float* W1i = (const float*)d_in[13];
  const float* W2i = (const float*)d_in[14];
  const float* gmm = (const float*)d_in[15];
  const float* btt = (const float*)d_in[16];
  const float* gW = (const float*)d_in[17];
  const float* oW = (const float*)d_in[18];

  char* ws = (char*)d_ws;
  size_t off = 0;
  auto alloc = [&](size_t bytes) {
    void* pp = ws + off;
    off += (bytes + 255) & ~(size_t)255;
    return pp;
  };
  const size_t MTOT = 16384ull;
  unsigned* bar = (unsigned*)alloc(32 * 64 * 4);
  float* alpb = (float*)alloc(MTOT * 8 * 4);
  float* etab = (float*)alloc(MTOT * 8 * 4);
  float* thetab = (float*)alloc(MTOT * 8 * 4);
  float* cosT = (float*)alloc(4096ull * 64 * 4);
  float* sinT = (float*)alloc(4096ull * 64 * 4);
  ushort* wtqh = (ushort*)alloc(1024ull * 1024 * 2);
  ushort* wtql = (ushort*)alloc(1024ull * 1024 * 2);
  ushort* wtkh = (ushort*)alloc(1024ull * 1024 * 2);
  ushort* wtkl = (ushort*)alloc(1024ull * 1024 * 2);
  ushort* wtvh = (ushort*)alloc(1024ull * 1024 * 2);
  ushort* wtvl = (ushort*)alloc(1024ull * 1024 * 2);
  ushort* wtgh = (ushort*)alloc(1024ull * 1024 * 2);
  ushort* wtgl = (ushort*)alloc(1024ull * 1024 * 2);
  ushort* wtoh = (ushort*)alloc(1024ull * 1024 * 2);
  ushort* wtol = (ushort*)alloc(1024ull * 1024 * 2);
  float* qh = (float*)alloc(MTOT * 1024 * 4);     // fp32 q; obuf overlays after use
  float* kh = (float*)alloc(MTOT * 1024 * 4);     // fp32 k; yh/yl overlay after scan
  float* vh = (float*)alloc(MTOT * 1024 * 4);     // fp32 v; gate overlays after scan
  ushort* xbh = (ushort*)alloc(4096ull * 1024 * 2);  // per-b pre-split x hi
  ushort* xbl = (ushort*)alloc(4096ull * 1024 * 2);  // per-b pre-split x lo

  // d_out time-multiplexed: [lin_q|lin_k|lin_v] (proj, 50.4MB); [p|o|z slots x2] (scan, 34MB)
  float* lin3 = (float*)d_out;
  float* pslots = (float*)d_out;
  float* oslots = pslots + 2ull * 32 * 8 * 8192;
  float* zslots = oslots + 2ull * 32 * 8 * 8192;
  float* obuf = qh;
  float* gate = vh;
  ushort* yh = (ushort*)kh;
  ushort* yl = yh + MTOT * 1024;

  dim3 tg5(16, 16, 5);
  cvt_wT_split5_kernel<<<tg5, 256, 0, stream>>>(Wq, Wk, Wv, gW, oW, wtqh, wtql, wtkh, wtkl, wtvh,
                                                wtvl, wtgh, wtgl, wtoh, wtol);
  rope_table_kernel<<<4096, 64, 0, stream>>>(cosT, sinT);
  proj_small_kernel<<<64, 256, 0, stream>>>(x, Wal, Wet, Wth, alpb, etab, thetab);

  dim3 gb3(32, 8, 3);
  for (int b = 0; b < 4; ++b) {
    const float* xb = x + (size_t)b * 4096 * 1024;
    split_x_kernel<<<1024, 256, 0, stream>>>(xb, xbh, xbl, 4096 * 1024 / 4);
    gemm_ps3_kernel<<<gb3, 256, 0, stream>>>(xbh, xbl, wtqh, wtql, wtkh, wtkl, wtvh, wtvl, lin3,
                                             4096, 1024);
    conv3_kernel<<<24576, 256, 0, stream>>>(lin3, cwq, cbq, cwk, cbk, cwv, cbv, cosT, sinT, qh, kh,
                                            vh, b);
  }

  hipMemsetAsync(bar, 0, 32 * 64 * 4, stream);
  hipFuncSetAttribute((const void*)scan_kernel, hipFuncAttributeMaxDynamicSharedMemorySize,
                      SCAN_LDS_BYTES);
  scan_kernel<<<GRIDN, 512, SCAN_LDS_BYTES, stream>>>(qh, kh, vh, thetab, etab, alpb, W1i, W2i,
                                                      gmm, btt, pslots, oslots, zslots, obuf, bar);

  dim3 gg(128, 8);
  gemm_split_kernel<1><<<gg, 256, 0, stream>>>(x, wtgh, wtgl, gate, 16384, 1024);
  post_kernel<<<16384, 256, 0, stream>>>(obuf, gate, gmm, btt, yh, yl);
  gemm_ps_kernel<<<gg, 256, 0, stream>>>(yh, yl, wtoh, wtol, (float*)d_out, 16384, 1024);
}